// Round 3
// baseline (1201.315 us; speedup 1.0000x reference)
//
#include <hip/hip_runtime.h>
#include <hip/hip_bf16.h>

// VAE with grid-GCN encoder, MI355X. Round 2: f32 inputs AND f32 output
// (out_npz size proves reference output dtype is float32).

#define BB 1024
#define HG 28
#define NN 784
#define KK 70
#define F3 48
#define HD 400
#define ZD 70
#define IMGD 784

typedef __hip_bfloat16 bf16;

__device__ __forceinline__ void stv(float* p, float v){ *p = v; }
__device__ __forceinline__ void stv(bf16* p, float v){ *p = __float2bfloat16(v); }

__device__ __forceinline__ float dinv_ij(int i, int j){
  int deg = 1 + (i>0) + (i<HG-1) + (j>0) + (j<HG-1);   // self-loop + 4-neighborhood
  return rsqrtf((float)deg);
}

// All three GCN layers fused, one block per (sample, half-grid slab of 14 rows).
// h1 (18 halo rows) and h2 (16 halo rows) live only in LDS; h3 -> global bf16.
__global__ __launch_bounds__(256)
void gcn_fused(const float* __restrict__ nodes,
               const float* __restrict__ W1, const float* __restrict__ b1,
               const float* __restrict__ W2, const float* __restrict__ b2,
               const float* __restrict__ W3, const float* __restrict__ b3,
               bf16* __restrict__ h3){
  __shared__ float h1s[18][HG][16];   // 32.25 KB
  __shared__ float h2s[16][HG][32];   // 57.3 KB
  __shared__ float W1s[2][16], W2s[16][32], W3s[32][48];
  __shared__ float b1s[16], b2s[32], b3s[48];
  int tid = threadIdx.x;
  if (tid < 32) W1s[tid>>4][tid&15] = W1[tid];
  for (int t = tid; t < 16*32; t += 256) W2s[t>>5][t&31] = W2[t];
  for (int t = tid; t < 32*48; t += 256) W3s[t/48][t%48] = W3[t];
  if (tid < 16) b1s[tid] = b1[tid];
  if (tid < 32) b2s[tid] = b2[tid];
  if (tid < 48) b3s[tid] = b3[tid];
  int b = blockIdx.x >> 1, s = blockIdx.x & 1;
  int base1 = s*14 - 2;          // first row held in h1s
  int base2 = s*14 - 1;          // first row held in h2s
  const float* nb = nodes + (size_t)b*NN*2;
  __syncthreads();

  // ---- layer 1: nodes (global) -> h1s
  {
    int r0 = max(0, base1), r1 = min(HG, base1+18);
    int cnt = (r1-r0)*HG;
    for (int t = tid; t < cnt; t += 256){
      int r = r0 + t/HG, j = t - (t/HG)*HG;
      float dn = dinv_ij(r,j);
      float a0 = dn*nb[(r*HG+j)*2+0], a1 = dn*nb[(r*HG+j)*2+1];
      if (r > 0)   { float w=dinv_ij(r-1,j); a0 += w*nb[((r-1)*HG+j)*2]; a1 += w*nb[((r-1)*HG+j)*2+1]; }
      if (r < HG-1){ float w=dinv_ij(r+1,j); a0 += w*nb[((r+1)*HG+j)*2]; a1 += w*nb[((r+1)*HG+j)*2+1]; }
      if (j > 0)   { float w=dinv_ij(r,j-1); a0 += w*nb[(r*HG+j-1)*2];   a1 += w*nb[(r*HG+j-1)*2+1]; }
      if (j < HG-1){ float w=dinv_ij(r,j+1); a0 += w*nb[(r*HG+j+1)*2];   a1 += w*nb[(r*HG+j+1)*2+1]; }
      a0 *= dn; a1 *= dn;
      float* o = h1s[r-base1][j];
      #pragma unroll
      for (int f=0; f<16; f++) o[f] = fmaxf(a0*W1s[0][f] + a1*W1s[1][f] + b1s[f], 0.f);
    }
  }
  __syncthreads();

  // ---- layer 2: h1s -> h2s
  {
    int r0 = max(0, base2), r1 = min(HG, base2+16);
    int cnt = (r1-r0)*HG;
    for (int t = tid; t < cnt; t += 256){
      int r = r0 + t/HG, j = t - (t/HG)*HG;
      float dn = dinv_ij(r,j);
      float agg[16];
      { const float* p = h1s[r-base1][j];
        #pragma unroll
        for (int f=0; f<16; f++) agg[f] = dn*p[f]; }
      if (r > 0)   { float w=dinv_ij(r-1,j); const float* p = h1s[r-1-base1][j];
        #pragma unroll
        for (int f=0; f<16; f++) agg[f] += w*p[f]; }
      if (r < HG-1){ float w=dinv_ij(r+1,j); const float* p = h1s[r+1-base1][j];
        #pragma unroll
        for (int f=0; f<16; f++) agg[f] += w*p[f]; }
      if (j > 0)   { float w=dinv_ij(r,j-1); const float* p = h1s[r-base1][j-1];
        #pragma unroll
        for (int f=0; f<16; f++) agg[f] += w*p[f]; }
      if (j < HG-1){ float w=dinv_ij(r,j+1); const float* p = h1s[r-base1][j+1];
        #pragma unroll
        for (int f=0; f<16; f++) agg[f] += w*p[f]; }
      #pragma unroll
      for (int f=0; f<16; f++) agg[f] *= dn;
      float* o = h2s[r-base2][j];
      for (int fo=0; fo<32; fo++){
        float sacc = b2s[fo];
        #pragma unroll
        for (int fi=0; fi<16; fi++) sacc += agg[fi]*W2s[fi][fo];
        o[fo] = fmaxf(sacc, 0.f);
      }
    }
  }
  __syncthreads();

  // ---- layer 3: h2s -> h3 (global, bf16)
  {
    for (int t = tid; t < 14*HG; t += 256){
      int r = s*14 + t/HG, j = t - (t/HG)*HG;
      float dn = dinv_ij(r,j);
      float agg[32];
      { const float* p = h2s[r-base2][j];
        #pragma unroll
        for (int f=0; f<32; f++) agg[f] = dn*p[f]; }
      if (r > 0)   { float w=dinv_ij(r-1,j); const float* p = h2s[r-1-base2][j];
        #pragma unroll
        for (int f=0; f<32; f++) agg[f] += w*p[f]; }
      if (r < HG-1){ float w=dinv_ij(r+1,j); const float* p = h2s[r+1-base2][j];
        #pragma unroll
        for (int f=0; f<32; f++) agg[f] += w*p[f]; }
      if (j > 0)   { float w=dinv_ij(r,j-1); const float* p = h2s[r-base2][j-1];
        #pragma unroll
        for (int f=0; f<32; f++) agg[f] += w*p[f]; }
      if (j < HG-1){ float w=dinv_ij(r,j+1); const float* p = h2s[r-base2][j+1];
        #pragma unroll
        for (int f=0; f<32; f++) agg[f] += w*p[f]; }
      #pragma unroll
      for (int f=0; f<32; f++) agg[f] *= dn;
      bf16* op = h3 + ((size_t)b*NN + r*HG + j)*F3;
      for (int fo=0; fo<F3; fo++){
        float sacc = b3s[fo];
        #pragma unroll
        for (int fi=0; fi<32; fi++) sacc += agg[fi]*W3s[fi][fo];
        op[fo] = __float2bfloat16(fmaxf(sacc, 0.f));
      }
    }
  }
}

// Fused gumbel-softmax + einsum('bnk,bnf->bkf'): one block per batch sample.
__global__ __launch_bounds__(256)
void softmax_einsum_kernel(const float* __restrict__ logits, const float* __restrict__ gumbel,
                           const bf16* __restrict__ h3, float* __restrict__ g){
  __shared__ float samp[112][80];
  __shared__ float hh[112][48];
  int b = blockIdx.x;
  int tid = threadIdx.x;
  int kg = tid >> 4, fg = tid & 15;     // 16 k-groups x 16 f-groups
  float acc[5][3] = {};
  for (int c0 = 0; c0 < NN; c0 += 112){
    int nl = tid >> 1, half = tid & 1;  // 2 threads per node, 35 k each
    if (nl < 112){
      size_t basei = ((size_t)b*NN + c0 + nl)*KK + half*35;
      float x[35];
      float m = -1e30f;
      #pragma unroll
      for (int t=0; t<35; t++){
        x[t] = 2.0f*(logits[basei+t] + gumbel[basei+t]);
        m = fmaxf(m, x[t]);
      }
      m = fmaxf(m, __shfl_xor(m, 1));
      float sum = 0.f;
      #pragma unroll
      for (int t=0; t<35; t++){ x[t] = __expf(x[t]-m); sum += x[t]; }
      sum += __shfl_xor(sum, 1);
      float r = 1.0f/sum;
      #pragma unroll
      for (int t=0; t<35; t++) samp[nl][half*35+t] = x[t]*r;
    }
    for (int id2 = tid; id2 < 112*F3; id2 += 256){   // coalesced h3 stage
      int n2 = id2 / F3, f2 = id2 - n2*F3;
      hh[n2][f2] = __bfloat162float(h3[((size_t)b*NN + c0 + n2)*F3 + f2]);
    }
    __syncthreads();
    for (int nn2 = 0; nn2 < 112; nn2++){
      float sv[5], hv[3];
      #pragma unroll
      for (int ki=0; ki<5; ki++) sv[ki] = samp[nn2][kg*5+ki];
      #pragma unroll
      for (int fi=0; fi<3; fi++) hv[fi] = hh[nn2][fg*3+fi];
      #pragma unroll
      for (int ki=0; ki<5; ki++)
        #pragma unroll
        for (int fi=0; fi<3; fi++) acc[ki][fi] += sv[ki]*hv[fi];
    }
    __syncthreads();
  }
  #pragma unroll
  for (int ki=0; ki<5; ki++){
    int k = kg*5 + ki;
    if (k < KK){
      #pragma unroll
      for (int fi=0; fi<3; fi++)
        g[(size_t)b*(KK*F3) + k*F3 + fg*3 + fi] = acc[ki][fi];
    }
  }
}

// Register-tiled dense: out = act(A[f32, MxK] @ W[f32, KxN] + b). 64x64 tile, 4x4/thread.
template<typename TOUT, int ACT>   // ACT: 0=relu, 1=sigmoid
__global__ __launch_bounds__(256)
void dense_kernel(const float* __restrict__ A, const float* __restrict__ W,
                  const float* __restrict__ bias, TOUT* __restrict__ out,
                  int M, int K, int Nn){
  __shared__ float As[16][65];
  __shared__ float Bs[16][64];
  int tx = threadIdx.x & 15, ty = threadIdx.x >> 4;
  int m0 = blockIdx.x*64, n0 = blockIdx.y*64;
  float acc[4][4] = {};
  for (int k0 = 0; k0 < K; k0 += 16){
    #pragma unroll
    for (int s=0; s<4; s++){
      int id = threadIdx.x + s*256;
      int kk = id & 15, mm = id >> 4;
      int gk = k0 + kk;
      As[kk][mm] = (gk < K) ? A[(size_t)(m0+mm)*K + gk] : 0.f;
    }
    #pragma unroll
    for (int s=0; s<4; s++){
      int id = threadIdx.x + s*256;
      int nn2 = id & 63, kk = id >> 6;
      int gk = k0 + kk, gn = n0 + nn2;
      Bs[kk][nn2] = (gk < K && gn < Nn) ? W[(size_t)gk*Nn + gn] : 0.f;
    }
    __syncthreads();
    #pragma unroll
    for (int kk=0; kk<16; kk++){
      float a[4], bv[4];
      #pragma unroll
      for (int i2=0; i2<4; i2++) a[i2] = As[kk][ty*4+i2];
      #pragma unroll
      for (int j2=0; j2<4; j2++) bv[j2] = Bs[kk][tx*4+j2];
      #pragma unroll
      for (int i2=0; i2<4; i2++)
        #pragma unroll
        for (int j2=0; j2<4; j2++) acc[i2][j2] += a[i2]*bv[j2];
    }
    __syncthreads();
  }
  #pragma unroll
  for (int j2=0; j2<4; j2++){
    int gn = n0 + tx*4 + j2;
    if (gn < Nn){
      float bb = bias[gn];
      #pragma unroll
      for (int i2=0; i2<4; i2++){
        float v = acc[i2][j2] + bb;
        if (ACT == 0) v = fmaxf(v, 0.f);
        else          v = 1.0f/(1.0f + __expf(-v));
        stv(out + (size_t)(m0 + ty*4 + i2)*Nn + gn, v);
      }
    }
  }
}

// mu/var heads + reparameterize, fused: one thread per (b, zi).
__global__ __launch_bounds__(256)
void latent_kernel(const float* __restrict__ e2,
                   const float* __restrict__ Wmu, const float* __restrict__ bmu,
                   const float* __restrict__ Wvar, const float* __restrict__ bvar,
                   const float* __restrict__ eps, float* __restrict__ z){
  int idx = blockIdx.x*256 + threadIdx.x;   // grid exact: 1024*70 = 280*256
  int b = idx / ZD, zi = idx - b*ZD;
  const float* er = e2 + (size_t)b*HD;
  float amu = 0.f, avr = 0.f;
  for (int j=0; j<HD; j++){
    float e = er[j];
    amu += e*Wmu[j*ZD + zi];
    avr += e*Wvar[j*ZD + zi];
  }
  float mu = amu + bmu[zi];
  float va = avr + bvar[zi];
  float sp = fmaxf(va, 0.f) + log1pf(__expf(-fabsf(va)));   // stable softplus
  z[idx] = mu + eps[idx]*sqrtf(sp + 1e-10f);
}

extern "C" void kernel_launch(void* const* d_in, const int* in_sizes, int n_in,
                              void* d_out, int out_size, void* d_ws, size_t ws_size,
                              hipStream_t stream){
  (void)in_sizes; (void)n_in; (void)out_size; (void)ws_size;
  const float* nodes  = (const float*)d_in[0];
  const float* logits = (const float*)d_in[1];
  const float* gumbel = (const float*)d_in[2];
  const float* eps    = (const float*)d_in[3];
  const float* W1 =(const float*)d_in[4],  *b1 =(const float*)d_in[5];
  const float* W2 =(const float*)d_in[6],  *b2 =(const float*)d_in[7];
  const float* W3 =(const float*)d_in[8],  *b3 =(const float*)d_in[9];
  const float* We1=(const float*)d_in[10], *be1=(const float*)d_in[11];
  const float* We2=(const float*)d_in[12], *be2=(const float*)d_in[13];
  const float* Wmu=(const float*)d_in[14], *bmu=(const float*)d_in[15];
  const float* Wvr=(const float*)d_in[16], *bvr=(const float*)d_in[17];
  const float* Wd1=(const float*)d_in[18], *bd1=(const float*)d_in[19];
  const float* Wd2=(const float*)d_in[20], *bd2=(const float*)d_in[21];
  // edge_src/edge_dst (d_in[22], d_in[23]) unused: grid graph handled analytically.

  char* ws = (char*)d_ws;
  // ws layout (bytes), total ~96 MB:
  bf16*  h3 = (bf16*)(ws);                 // B*N*48*2       = 77,070,336
  float* g  = (float*)(ws + 77070336);     // B*3360*4       = 13,762,560
  float* e1 = (float*)(ws + 90832896);     // B*400*4        =  1,638,400
  float* e2 = (float*)(ws + 92471296);     // B*400*4
  float* zb = (float*)(ws + 94109696);     // B*70*4         =    286,720
  float* dd = (float*)(ws + 94396416);     // B*400*4
  float* out = (float*)d_out;              // reference output dtype is float32

  gcn_fused<<<2048, 256, 0, stream>>>(nodes, W1, b1, W2, b2, W3, b3, h3);
  softmax_einsum_kernel<<<1024, 256, 0, stream>>>(logits, gumbel, h3, g);
  dense_kernel<float, 0><<<dim3(16, 7), 256, 0, stream>>>(g,  We1, be1, e1, 1024, 3360, 400);
  dense_kernel<float, 0><<<dim3(16, 7), 256, 0, stream>>>(e1, We2, be2, e2, 1024, 400, 400);
  latent_kernel<<<280, 256, 0, stream>>>(e2, Wmu, bmu, Wvr, bvr, eps, zb);
  dense_kernel<float, 0><<<dim3(16, 7), 256, 0, stream>>>(zb, Wd1, bd1, dd, 1024, 70, 400);
  dense_kernel<float, 1><<<dim3(16, 13), 256, 0, stream>>>(dd, Wd2, bd2, out, 1024, 400, 784);
}

// Round 4
// 611.119 us; speedup vs baseline: 1.9658x; 1.9658x over previous
//
#include <hip/hip_runtime.h>
#include <hip/hip_bf16.h>

// VAE with grid-GCN encoder, MI355X. Round 3: split-K + register-prefetch dense,
// coalesced vectorized softmax/einsum staging. f32 in/out, h3 bf16 in ws.

#define BB 1024
#define HG 28
#define NN 784
#define KK 70
#define F3 48
#define HD 400
#define ZD 70
#define IMGD 784

typedef __hip_bfloat16 bf16;

__device__ __forceinline__ float dinv_ij(int i, int j){
  int deg = 1 + (i>0) + (i<HG-1) + (j>0) + (j<HG-1);   // self-loop + 4-neighborhood
  return rsqrtf((float)deg);
}

// All three GCN layers fused, one block per (sample, half-grid slab of 14 rows).
// h1 (18 halo rows) and h2 (16 halo rows) live only in LDS; h3 -> global bf16.
__global__ __launch_bounds__(256)
void gcn_fused(const float* __restrict__ nodes,
               const float* __restrict__ W1, const float* __restrict__ b1,
               const float* __restrict__ W2, const float* __restrict__ b2,
               const float* __restrict__ W3, const float* __restrict__ b3,
               bf16* __restrict__ h3){
  __shared__ float h1s[18][HG][16];   // 32.25 KB
  __shared__ float h2s[16][HG][32];   // 57.3 KB
  __shared__ float W1s[2][16], W2s[16][32], W3s[32][48];
  __shared__ float b1s[16], b2s[32], b3s[48];
  int tid = threadIdx.x;
  if (tid < 32) W1s[tid>>4][tid&15] = W1[tid];
  for (int t = tid; t < 16*32; t += 256) W2s[t>>5][t&31] = W2[t];
  for (int t = tid; t < 32*48; t += 256) W3s[t/48][t%48] = W3[t];
  if (tid < 16) b1s[tid] = b1[tid];
  if (tid < 32) b2s[tid] = b2[tid];
  if (tid < 48) b3s[tid] = b3[tid];
  int b = blockIdx.x >> 1, s = blockIdx.x & 1;
  int base1 = s*14 - 2;          // first row held in h1s
  int base2 = s*14 - 1;          // first row held in h2s
  const float* nb = nodes + (size_t)b*NN*2;
  __syncthreads();

  // ---- layer 1: nodes (global) -> h1s
  {
    int r0 = max(0, base1), r1 = min(HG, base1+18);
    int cnt = (r1-r0)*HG;
    for (int t = tid; t < cnt; t += 256){
      int r = r0 + t/HG, j = t - (t/HG)*HG;
      float dn = dinv_ij(r,j);
      float a0 = dn*nb[(r*HG+j)*2+0], a1 = dn*nb[(r*HG+j)*2+1];
      if (r > 0)   { float w=dinv_ij(r-1,j); a0 += w*nb[((r-1)*HG+j)*2]; a1 += w*nb[((r-1)*HG+j)*2+1]; }
      if (r < HG-1){ float w=dinv_ij(r+1,j); a0 += w*nb[((r+1)*HG+j)*2]; a1 += w*nb[((r+1)*HG+j)*2+1]; }
      if (j > 0)   { float w=dinv_ij(r,j-1); a0 += w*nb[(r*HG+j-1)*2];   a1 += w*nb[(r*HG+j-1)*2+1]; }
      if (j < HG-1){ float w=dinv_ij(r,j+1); a0 += w*nb[(r*HG+j+1)*2];   a1 += w*nb[(r*HG+j+1)*2+1]; }
      a0 *= dn; a1 *= dn;
      float* o = h1s[r-base1][j];
      #pragma unroll
      for (int f=0; f<16; f++) o[f] = fmaxf(a0*W1s[0][f] + a1*W1s[1][f] + b1s[f], 0.f);
    }
  }
  __syncthreads();

  // ---- layer 2: h1s -> h2s
  {
    int r0 = max(0, base2), r1 = min(HG, base2+16);
    int cnt = (r1-r0)*HG;
    for (int t = tid; t < cnt; t += 256){
      int r = r0 + t/HG, j = t - (t/HG)*HG;
      float dn = dinv_ij(r,j);
      float agg[16];
      { const float* p = h1s[r-base1][j];
        #pragma unroll
        for (int f=0; f<16; f++) agg[f] = dn*p[f]; }
      if (r > 0)   { float w=dinv_ij(r-1,j); const float* p = h1s[r-1-base1][j];
        #pragma unroll
        for (int f=0; f<16; f++) agg[f] += w*p[f]; }
      if (r < HG-1){ float w=dinv_ij(r+1,j); const float* p = h1s[r+1-base1][j];
        #pragma unroll
        for (int f=0; f<16; f++) agg[f] += w*p[f]; }
      if (j > 0)   { float w=dinv_ij(r,j-1); const float* p = h1s[r-base1][j-1];
        #pragma unroll
        for (int f=0; f<16; f++) agg[f] += w*p[f]; }
      if (j < HG-1){ float w=dinv_ij(r,j+1); const float* p = h1s[r-base1][j+1];
        #pragma unroll
        for (int f=0; f<16; f++) agg[f] += w*p[f]; }
      #pragma unroll
      for (int f=0; f<16; f++) agg[f] *= dn;
      float* o = h2s[r-base2][j];
      for (int fo=0; fo<32; fo++){
        float sacc = b2s[fo];
        #pragma unroll
        for (int fi=0; fi<16; fi++) sacc += agg[fi]*W2s[fi][fo];
        o[fo] = fmaxf(sacc, 0.f);
      }
    }
  }
  __syncthreads();

  // ---- layer 3: h2s -> h3 (global, bf16)
  {
    for (int t = tid; t < 14*HG; t += 256){
      int r = s*14 + t/HG, j = t - (t/HG)*HG;
      float dn = dinv_ij(r,j);
      float agg[32];
      { const float* p = h2s[r-base2][j];
        #pragma unroll
        for (int f=0; f<32; f++) agg[f] = dn*p[f]; }
      if (r > 0)   { float w=dinv_ij(r-1,j); const float* p = h2s[r-1-base2][j];
        #pragma unroll
        for (int f=0; f<32; f++) agg[f] += w*p[f]; }
      if (r < HG-1){ float w=dinv_ij(r+1,j); const float* p = h2s[r+1-base2][j];
        #pragma unroll
        for (int f=0; f<32; f++) agg[f] += w*p[f]; }
      if (j > 0)   { float w=dinv_ij(r,j-1); const float* p = h2s[r-base2][j-1];
        #pragma unroll
        for (int f=0; f<32; f++) agg[f] += w*p[f]; }
      if (j < HG-1){ float w=dinv_ij(r,j+1); const float* p = h2s[r-base2][j+1];
        #pragma unroll
        for (int f=0; f<32; f++) agg[f] += w*p[f]; }
      #pragma unroll
      for (int f=0; f<32; f++) agg[f] *= dn;
      bf16* op = h3 + ((size_t)b*NN + r*HG + j)*F3;
      for (int fo=0; fo<F3; fo++){
        float sacc = b3s[fo];
        #pragma unroll
        for (int fi=0; fi<32; fi++) sacc += agg[fi]*W3s[fi][fo];
        op[fo] = __float2bfloat16(fmaxf(sacc, 0.f));
      }
    }
  }
}

// Fused gumbel-softmax + einsum('bnk,bnf->bkf'): one block per batch sample.
// Chunk of 112 nodes staged via coalesced float4 loads (the (n,k) plane is contiguous).
__global__ __launch_bounds__(256)
void softmax_einsum_kernel(const float* __restrict__ logits, const float* __restrict__ gumbel,
                           const bf16* __restrict__ h3, float* __restrict__ g){
  __shared__ float samp[112][81];   // padded to 81 (odd stride -> conflict-free col access)
  __shared__ float hh[112][48];
  int b = blockIdx.x;
  int tid = threadIdx.x;
  int kg = tid >> 4, fg = tid & 15;     // 16 k-groups x 16 f-groups
  float acc[5][3] = {};
  for (int c0 = 0; c0 < NN; c0 += 112){
    // ---- stage 2*(logits+gumbel), fully coalesced float4
    const float4* l4 = (const float4*)(logits + ((size_t)b*NN + c0)*KK);
    const float4* g4 = (const float4*)(gumbel + ((size_t)b*NN + c0)*KK);
    for (int t = tid; t < 1960; t += 256){       // 112*70/4
      float4 lv = l4[t], gv = g4[t];
      float xs[4] = {2.f*(lv.x+gv.x), 2.f*(lv.y+gv.y), 2.f*(lv.z+gv.z), 2.f*(lv.w+gv.w)};
      int e = t*4;
      #pragma unroll
      for (int i2=0;i2<4;i2++){
        int n = (e+i2)/KK, k = (e+i2) - KK*n;
        samp[n][k] = xs[i2];
      }
    }
    // ---- stage h3 via 16B loads (8 bf16 each)
    const uint4* h4 = (const uint4*)(h3 + ((size_t)b*NN + c0)*F3);
    for (int t = tid; t < 672; t += 256){        // 112*48/8
      uint4 v = h4[t];
      int n = t/6, f0 = (t - n*6)*8;
      unsigned vv[4] = {v.x, v.y, v.z, v.w};
      #pragma unroll
      for (int i2=0;i2<4;i2++){
        hh[n][f0+2*i2]   = __uint_as_float((vv[i2] & 0xFFFFu) << 16);
        hh[n][f0+2*i2+1] = __uint_as_float(vv[i2] & 0xFFFF0000u);
      }
    }
    __syncthreads();
    // ---- softmax in-place: 2 threads per node, 35 classes each
    int nl = tid >> 1, half = tid & 1;
    if (nl < 112){
      float x[35];
      float m = -1e30f;
      #pragma unroll
      for (int t=0; t<35; t++){ x[t] = samp[nl][half*35+t]; m = fmaxf(m, x[t]); }
      m = fmaxf(m, __shfl_xor(m, 1));
      float sum = 0.f;
      #pragma unroll
      for (int t=0; t<35; t++){ x[t] = __expf(x[t]-m); sum += x[t]; }
      sum += __shfl_xor(sum, 1);
      float r = 1.0f/sum;
      #pragma unroll
      for (int t=0; t<35; t++) samp[nl][half*35+t] = x[t]*r;
    }
    __syncthreads();
    // ---- outer-product accumulate
    for (int nn2 = 0; nn2 < 112; nn2++){
      float sv[5], hv[3];
      #pragma unroll
      for (int ki=0; ki<5; ki++) sv[ki] = samp[nn2][kg*5+ki];
      #pragma unroll
      for (int fi=0; fi<3; fi++) hv[fi] = hh[nn2][fg*3+fi];
      #pragma unroll
      for (int ki=0; ki<5; ki++)
        #pragma unroll
        for (int fi=0; fi<3; fi++) acc[ki][fi] += sv[ki]*hv[fi];
    }
    __syncthreads();
  }
  #pragma unroll
  for (int ki=0; ki<5; ki++){
    int k = kg*5 + ki;
    if (k < KK){
      #pragma unroll
      for (int fi=0; fi<3; fi++)
        g[(size_t)b*(KK*F3) + k*F3 + fg*3 + fi] = acc[ki][fi];
    }
  }
}

// Register-prefetch dense: out = act(A[f32, MxK] @ W[f32, KxN] + b).
// 64x64 tile, 4x4/thread, optional split-K via blockIdx.z (ACT==2: raw partial, no bias).
template<int ACT>   // 0=relu, 1=sigmoid, 2=partial (no bias/act)
__global__ __launch_bounds__(256)
void dense_kernel(const float* __restrict__ A, const float* __restrict__ W,
                  const float* __restrict__ bias, float* __restrict__ out,
                  int M, int K, int Nn, int kChunk){
  __shared__ float As[16][65];
  __shared__ float Bs[16][64];
  int tx = threadIdx.x & 15, ty = threadIdx.x >> 4;
  int m0 = blockIdx.x*64, n0 = blockIdx.y*64;
  int ks = blockIdx.z * kChunk;
  int ke = min(K, ks + kChunk);
  int a_kk = threadIdx.x & 15, a_mm = threadIdx.x >> 4;   // A loader coords
  int b_nn = threadIdx.x & 63, b_k0 = threadIdx.x >> 6;   // B loader coords
  float ra[4], rb[4];
  float acc[4][4] = {};

  // prologue load (k-tile 0 of this chunk)
  #pragma unroll
  for (int s=0; s<4; s++){
    int gk = ks + a_kk;
    ra[s] = (gk < ke) ? A[(size_t)(m0 + a_mm + s*16)*K + gk] : 0.f;
  }
  #pragma unroll
  for (int s=0; s<4; s++){
    int gk = ks + b_k0 + s*4, gn = n0 + b_nn;
    rb[s] = (gk < ke && gn < Nn) ? W[(size_t)gk*Nn + gn] : 0.f;
  }

  for (int k0 = ks; k0 < ke; k0 += 16){
    #pragma unroll
    for (int s=0; s<4; s++) As[a_kk][a_mm + s*16] = ra[s];
    #pragma unroll
    for (int s=0; s<4; s++) Bs[b_k0 + s*4][b_nn] = rb[s];
    __syncthreads();
    // prefetch next k-tile while computing this one
    if (k0 + 16 < ke){
      #pragma unroll
      for (int s=0; s<4; s++){
        int gk = k0 + 16 + a_kk;
        ra[s] = (gk < ke) ? A[(size_t)(m0 + a_mm + s*16)*K + gk] : 0.f;
      }
      #pragma unroll
      for (int s=0; s<4; s++){
        int gk = k0 + 16 + b_k0 + s*4, gn = n0 + b_nn;
        rb[s] = (gk < ke && gn < Nn) ? W[(size_t)gk*Nn + gn] : 0.f;
      }
    }
    #pragma unroll
    for (int kk=0; kk<16; kk++){
      float a[4], bv[4];
      #pragma unroll
      for (int i2=0; i2<4; i2++) a[i2] = As[kk][ty*4+i2];
      #pragma unroll
      for (int j2=0; j2<4; j2++) bv[j2] = Bs[kk][tx*4+j2];
      #pragma unroll
      for (int i2=0; i2<4; i2++)
        #pragma unroll
        for (int j2=0; j2<4; j2++) acc[i2][j2] += a[i2]*bv[j2];
    }
    __syncthreads();
  }

  if (ACT == 2){
    float* po = out + (size_t)blockIdx.z*M*Nn;
    #pragma unroll
    for (int j2=0; j2<4; j2++){
      int gn = n0 + tx*4 + j2;
      if (gn < Nn){
        #pragma unroll
        for (int i2=0; i2<4; i2++)
          po[(size_t)(m0 + ty*4 + i2)*Nn + gn] = acc[i2][j2];
      }
    }
  } else {
    #pragma unroll
    for (int j2=0; j2<4; j2++){
      int gn = n0 + tx*4 + j2;
      if (gn < Nn){
        float bb = bias[gn];
        #pragma unroll
        for (int i2=0; i2<4; i2++){
          float v = acc[i2][j2] + bb;
          v = (ACT == 0) ? fmaxf(v, 0.f) : 1.0f/(1.0f + __expf(-v));
          out[(size_t)(m0 + ty*4 + i2)*Nn + gn] = v;
        }
      }
    }
  }
}

// split-K partial reduction + bias + relu
__global__ __launch_bounds__(256)
void reduce_bias_relu(const float* __restrict__ part, const float* __restrict__ bias,
                      float* __restrict__ out, int M, int Nn, int S){
  int idx = blockIdx.x*256 + threadIdx.x;
  if (idx >= M*Nn) return;
  int n = idx % Nn;
  float s = bias[n];
  for (int i=0; i<S; i++) s += part[(size_t)i*M*Nn + idx];
  out[idx] = fmaxf(s, 0.f);
}

// mu/var heads + reparameterize, fused: one thread per (b, zi).
__global__ __launch_bounds__(256)
void latent_kernel(const float* __restrict__ e2,
                   const float* __restrict__ Wmu, const float* __restrict__ bmu,
                   const float* __restrict__ Wvar, const float* __restrict__ bvar,
                   const float* __restrict__ eps, float* __restrict__ z){
  int idx = blockIdx.x*256 + threadIdx.x;   // grid exact: 1024*70 = 280*256
  int b = idx / ZD, zi = idx - b*ZD;
  const float* er = e2 + (size_t)b*HD;
  float amu = 0.f, avr = 0.f;
  for (int j=0; j<HD; j++){
    float e = er[j];
    amu += e*Wmu[j*ZD + zi];
    avr += e*Wvar[j*ZD + zi];
  }
  float mu = amu + bmu[zi];
  float va = avr + bvar[zi];
  float sp = fmaxf(va, 0.f) + log1pf(__expf(-fabsf(va)));   // stable softplus
  z[idx] = mu + eps[idx]*sqrtf(sp + 1e-10f);
}

extern "C" void kernel_launch(void* const* d_in, const int* in_sizes, int n_in,
                              void* d_out, int out_size, void* d_ws, size_t ws_size,
                              hipStream_t stream){
  (void)in_sizes; (void)n_in; (void)out_size; (void)ws_size;
  const float* nodes  = (const float*)d_in[0];
  const float* logits = (const float*)d_in[1];
  const float* gumbel = (const float*)d_in[2];
  const float* eps    = (const float*)d_in[3];
  const float* W1 =(const float*)d_in[4],  *b1 =(const float*)d_in[5];
  const float* W2 =(const float*)d_in[6],  *b2 =(const float*)d_in[7];
  const float* W3 =(const float*)d_in[8],  *b3 =(const float*)d_in[9];
  const float* We1=(const float*)d_in[10], *be1=(const float*)d_in[11];
  const float* We2=(const float*)d_in[12], *be2=(const float*)d_in[13];
  const float* Wmu=(const float*)d_in[14], *bmu=(const float*)d_in[15];
  const float* Wvr=(const float*)d_in[16], *bvr=(const float*)d_in[17];
  const float* Wd1=(const float*)d_in[18], *bd1=(const float*)d_in[19];
  const float* Wd2=(const float*)d_in[20], *bd2=(const float*)d_in[21];
  // edge_src/edge_dst (d_in[22], d_in[23]) unused: grid graph handled analytically.

  char* ws = (char*)d_ws;
  // ws layout (bytes), total ~96 MB:
  bf16*  h3 = (bf16*)(ws);                 // B*N*48*2       = 77,070,336
  float* g  = (float*)(ws + 77070336);     // B*3360*4       = 13,762,560
  float* e1 = (float*)(ws + 90832896);     // B*400*4        =  1,638,400
  float* e2 = (float*)(ws + 92471296);     // B*400*4
  float* zb = (float*)(ws + 94109696);     // B*70*4         =    286,720
  float* dd = (float*)(ws + 94396416);     // B*400*4
  float* part = (float*)(ws);              // 8*1024*400*4 = 13.1 MB, aliases h3 (dead by then)
  float* out = (float*)d_out;

  gcn_fused<<<2048, 256, 0, stream>>>(nodes, W1, b1, W2, b2, W3, b3, h3);
  softmax_einsum_kernel<<<1024, 256, 0, stream>>>(logits, gumbel, h3, g);
  // We1: M=1024, K=3360, N=400, split-K x8 (chunk 432 = 27*16)
  dense_kernel<2><<<dim3(16, 7, 8), 256, 0, stream>>>(g, We1, nullptr, part, 1024, 3360, 400, 432);
  reduce_bias_relu<<<1600, 256, 0, stream>>>(part, be1, e1, 1024, 400, 8);
  dense_kernel<0><<<dim3(16, 7, 1), 256, 0, stream>>>(e1, We2, be2, e2, 1024, 400, 400, 400);
  latent_kernel<<<280, 256, 0, stream>>>(e2, Wmu, bmu, Wvr, bvr, eps, zb);
  dense_kernel<0><<<dim3(16, 7, 1), 256, 0, stream>>>(zb, Wd1, bd1, dd, 1024, 70, 400, 70);
  dense_kernel<1><<<dim3(16, 13, 1), 256, 0, stream>>>(dd, Wd2, bd2, out, 1024, 400, 784, 400);
}

// Round 5
// 532.346 us; speedup vs baseline: 2.2566x; 1.1480x over previous
//
#include <hip/hip_runtime.h>
#include <hip/hip_bf16.h>

// VAE with grid-GCN encoder, MI355X. Round 4: feature-major LDS GCN
// (conflict-free), quarter-grid slabs for 2 blocks/CU occupancy.

#define BB 1024
#define HG 28
#define NN 784
#define KK 70
#define F3 48
#define HD 400
#define ZD 70
#define IMGD 784

typedef __hip_bfloat16 bf16;

__device__ __forceinline__ float dinv_ij(int i, int j){
  int deg = 1 + (i>0) + (i<HG-1) + (j>0) + (j<HG-1);   // self-loop + 4-neighborhood
  return rsqrtf((float)deg);
}

__device__ __forceinline__ unsigned pk2(float a, float b){
  union { bf16 h; unsigned short u; } ua, ub;
  ua.h = __float2bfloat16(a); ub.h = __float2bfloat16(b);
  return ((unsigned)ub.u << 16) | ua.u;
}

// Three GCN layers fused. One block per (sample, 7-row slab). Feature-major LDS:
// lanes index consecutive nodes -> conflict-free; weight reads are wave-uniform
// broadcasts. Halo rows outside the grid are zero-filled (deg-normalization is
// analytic, so zero contributions are exact).
__global__ __launch_bounds__(256)
void gcn_fused(const float* __restrict__ nodes,
               const float* __restrict__ W1, const float* __restrict__ b1,
               const float* __restrict__ W2, const float* __restrict__ b2,
               const float* __restrict__ W3, const float* __restrict__ b3,
               bf16* __restrict__ h3){
  __shared__ float h1s[16][308];   // 11 rows x 28 cols, rows base1..base1+10
  __shared__ float h2s[32][252];   // 9 rows x 28 cols,  rows base2..base2+8
  __shared__ float W1s[2][16], b1s[16];
  __shared__ float W2s[16][32], b2s[32];
  __shared__ float W3s[32][48], b3s[48];
  int tid = threadIdx.x;
  if (tid < 32) W1s[tid>>4][tid&15] = W1[tid];
  for (int t = tid; t < 16*32; t += 256) W2s[t>>5][t&31] = W2[t];
  for (int t = tid; t < 32*48; t += 256) W3s[t/48][t%48] = W3[t];
  if (tid < 16) b1s[tid] = b1[tid];
  if (tid < 32) b2s[tid] = b2[tid];
  if (tid < 48) b3s[tid] = b3[tid];

  int b = blockIdx.x >> 2, s = blockIdx.x & 3;
  int base3 = s*7;           // 7 output rows
  int base2 = base3 - 1;     // 9 rows in h2s
  int base1 = base3 - 2;     // 11 rows in h1s
  const float* nb = nodes + (size_t)b*NN*2;
  __syncthreads();

  // ---- layer 1: nodes (global, L3-resident) -> h1s[16][308]
  for (int t = tid; t < 308; t += 256){
    int lr = t/28, j = t - lr*28;
    int r = base1 + lr;
    if (r < 0 || r >= HG){
      #pragma unroll
      for (int f=0; f<16; f++) h1s[f][t] = 0.f;
    } else {
      float dn = dinv_ij(r,j);
      float a0 = dn*nb[(r*HG+j)*2+0], a1 = dn*nb[(r*HG+j)*2+1];
      if (r > 0)   { float w=dinv_ij(r-1,j); a0 += w*nb[((r-1)*HG+j)*2]; a1 += w*nb[((r-1)*HG+j)*2+1]; }
      if (r < HG-1){ float w=dinv_ij(r+1,j); a0 += w*nb[((r+1)*HG+j)*2]; a1 += w*nb[((r+1)*HG+j)*2+1]; }
      if (j > 0)   { float w=dinv_ij(r,j-1); a0 += w*nb[(r*HG+j-1)*2];   a1 += w*nb[(r*HG+j-1)*2+1]; }
      if (j < HG-1){ float w=dinv_ij(r,j+1); a0 += w*nb[(r*HG+j+1)*2];   a1 += w*nb[(r*HG+j+1)*2+1]; }
      a0 *= dn; a1 *= dn;
      #pragma unroll
      for (int f=0; f<16; f++)
        h1s[f][t] = fmaxf(a0*W1s[0][f] + a1*W1s[1][f] + b1s[f], 0.f);
    }
  }
  __syncthreads();

  // ---- layer 2: h1s -> h2s[32][252]
  for (int t = tid; t < 252; t += 256){
    int lr = t/28, j = t - lr*28;
    int r = base2 + lr;
    if (r < 0 || r >= HG){
      #pragma unroll
      for (int f=0; f<32; f++) h2s[f][t] = 0.f;
    } else {
      int ln = (lr+1)*28 + j;            // h1s slot for (r, j)
      float dn = dinv_ij(r,j);
      float wu = dinv_ij(r-1,j), wd = dinv_ij(r+1,j);
      float wl = (j>0)    ? dinv_ij(r,j-1) : 0.f;
      float wr = (j<HG-1) ? dinv_ij(r,j+1) : 0.f;
      float agg[16];
      #pragma unroll
      for (int f=0; f<16; f++){
        float v = dn*h1s[f][ln] + wu*h1s[f][ln-28] + wd*h1s[f][ln+28];
        if (j>0)    v += wl*h1s[f][ln-1];
        if (j<HG-1) v += wr*h1s[f][ln+1];
        agg[f] = v*dn;
      }
      #pragma unroll
      for (int fog=0; fog<8; fog++){
        float4 acc = *(const float4*)&b2s[fog*4];
        #pragma unroll
        for (int fi=0; fi<16; fi++){
          float4 w = *(const float4*)&W2s[fi][fog*4];
          float a = agg[fi];
          acc.x += a*w.x; acc.y += a*w.y; acc.z += a*w.z; acc.w += a*w.w;
        }
        h2s[fog*4+0][t] = fmaxf(acc.x, 0.f);
        h2s[fog*4+1][t] = fmaxf(acc.y, 0.f);
        h2s[fog*4+2][t] = fmaxf(acc.z, 0.f);
        h2s[fog*4+3][t] = fmaxf(acc.w, 0.f);
      }
    }
  }
  __syncthreads();

  // ---- layer 3: h2s -> h3 (global, packed bf16)
  for (int t = tid; t < 196; t += 256){
    int lr = t/28, j = t - lr*28;
    int r = base3 + lr;                  // always in [0,28)
    int ln = (lr+1)*28 + j;              // h2s slot for (r, j)
    float dn = dinv_ij(r,j);
    float wu = dinv_ij(r-1,j), wd = dinv_ij(r+1,j);
    float wl = (j>0)    ? dinv_ij(r,j-1) : 0.f;
    float wr = (j<HG-1) ? dinv_ij(r,j+1) : 0.f;
    float agg[32];
    #pragma unroll
    for (int f=0; f<32; f++){
      float v = dn*h2s[f][ln] + wu*h2s[f][ln-28] + wd*h2s[f][ln+28];
      if (j>0)    v += wl*h2s[f][ln-1];
      if (j<HG-1) v += wr*h2s[f][ln+1];
      agg[f] = v*dn;
    }
    uint2* op = (uint2*)(h3 + ((size_t)b*NN + r*HG + j)*F3);
    #pragma unroll
    for (int fog=0; fog<12; fog++){
      float4 acc = *(const float4*)&b3s[fog*4];
      #pragma unroll
      for (int fi=0; fi<32; fi++){
        float4 w = *(const float4*)&W3s[fi][fog*4];
        float a = agg[fi];
        acc.x += a*w.x; acc.y += a*w.y; acc.z += a*w.z; acc.w += a*w.w;
      }
      uint2 pv;
      pv.x = pk2(fmaxf(acc.x,0.f), fmaxf(acc.y,0.f));
      pv.y = pk2(fmaxf(acc.z,0.f), fmaxf(acc.w,0.f));
      op[fog] = pv;
    }
  }
}

// Fused gumbel-softmax + einsum('bnk,bnf->bkf'): one block per batch sample.
// Chunk of 112 nodes staged via coalesced float4 loads (the (n,k) plane is contiguous).
__global__ __launch_bounds__(256)
void softmax_einsum_kernel(const float* __restrict__ logits, const float* __restrict__ gumbel,
                           const bf16* __restrict__ h3, float* __restrict__ g){
  __shared__ float samp[112][81];   // padded to 81 (odd stride -> conflict-free col access)
  __shared__ float hh[112][48];
  int b = blockIdx.x;
  int tid = threadIdx.x;
  int kg = tid >> 4, fg = tid & 15;     // 16 k-groups x 16 f-groups
  float acc[5][3] = {};
  for (int c0 = 0; c0 < NN; c0 += 112){
    // ---- stage 2*(logits+gumbel), fully coalesced float4
    const float4* l4 = (const float4*)(logits + ((size_t)b*NN + c0)*KK);
    const float4* g4 = (const float4*)(gumbel + ((size_t)b*NN + c0)*KK);
    for (int t = tid; t < 1960; t += 256){       // 112*70/4
      float4 lv = l4[t], gv = g4[t];
      float xs[4] = {2.f*(lv.x+gv.x), 2.f*(lv.y+gv.y), 2.f*(lv.z+gv.z), 2.f*(lv.w+gv.w)};
      int e = t*4;
      #pragma unroll
      for (int i2=0;i2<4;i2++){
        int n = (e+i2)/KK, k = (e+i2) - KK*n;
        samp[n][k] = xs[i2];
      }
    }
    // ---- stage h3 via 16B loads (8 bf16 each)
    const uint4* h4 = (const uint4*)(h3 + ((size_t)b*NN + c0)*F3);
    for (int t = tid; t < 672; t += 256){        // 112*48/8
      uint4 v = h4[t];
      int n = t/6, f0 = (t - n*6)*8;
      unsigned vv[4] = {v.x, v.y, v.z, v.w};
      #pragma unroll
      for (int i2=0;i2<4;i2++){
        hh[n][f0+2*i2]   = __uint_as_float((vv[i2] & 0xFFFFu) << 16);
        hh[n][f0+2*i2+1] = __uint_as_float(vv[i2] & 0xFFFF0000u);
      }
    }
    __syncthreads();
    // ---- softmax in-place: 2 threads per node, 35 classes each
    int nl = tid >> 1, half = tid & 1;
    if (nl < 112){
      float x[35];
      float m = -1e30f;
      #pragma unroll
      for (int t=0; t<35; t++){ x[t] = samp[nl][half*35+t]; m = fmaxf(m, x[t]); }
      m = fmaxf(m, __shfl_xor(m, 1));
      float sum = 0.f;
      #pragma unroll
      for (int t=0; t<35; t++){ x[t] = __expf(x[t]-m); sum += x[t]; }
      sum += __shfl_xor(sum, 1);
      float r = 1.0f/sum;
      #pragma unroll
      for (int t=0; t<35; t++) samp[nl][half*35+t] = x[t]*r;
    }
    __syncthreads();
    // ---- outer-product accumulate
    for (int nn2 = 0; nn2 < 112; nn2++){
      float sv[5], hv[3];
      #pragma unroll
      for (int ki=0; ki<5; ki++) sv[ki] = samp[nn2][kg*5+ki];
      #pragma unroll
      for (int fi=0; fi<3; fi++) hv[fi] = hh[nn2][fg*3+fi];
      #pragma unroll
      for (int ki=0; ki<5; ki++)
        #pragma unroll
        for (int fi=0; fi<3; fi++) acc[ki][fi] += sv[ki]*hv[fi];
    }
    __syncthreads();
  }
  #pragma unroll
  for (int ki=0; ki<5; ki++){
    int k = kg*5 + ki;
    if (k < KK){
      #pragma unroll
      for (int fi=0; fi<3; fi++)
        g[(size_t)b*(KK*F3) + k*F3 + fg*3 + fi] = acc[ki][fi];
    }
  }
}

// Register-prefetch dense: out = act(A[f32, MxK] @ W[f32, KxN] + b).
// 64x64 tile, 4x4/thread, optional split-K via blockIdx.z (ACT==2: raw partial, no bias).
template<int ACT>   // 0=relu, 1=sigmoid, 2=partial (no bias/act)
__global__ __launch_bounds__(256)
void dense_kernel(const float* __restrict__ A, const float* __restrict__ W,
                  const float* __restrict__ bias, float* __restrict__ out,
                  int M, int K, int Nn, int kChunk){
  __shared__ float As[16][65];
  __shared__ float Bs[16][64];
  int tx = threadIdx.x & 15, ty = threadIdx.x >> 4;
  int m0 = blockIdx.x*64, n0 = blockIdx.y*64;
  int ks = blockIdx.z * kChunk;
  int ke = min(K, ks + kChunk);
  int a_kk = threadIdx.x & 15, a_mm = threadIdx.x >> 4;   // A loader coords
  int b_nn = threadIdx.x & 63, b_k0 = threadIdx.x >> 6;   // B loader coords
  float ra[4], rb[4];
  float acc[4][4] = {};

  // prologue load (k-tile 0 of this chunk)
  #pragma unroll
  for (int s=0; s<4; s++){
    int gk = ks + a_kk;
    ra[s] = (gk < ke) ? A[(size_t)(m0 + a_mm + s*16)*K + gk] : 0.f;
  }
  #pragma unroll
  for (int s=0; s<4; s++){
    int gk = ks + b_k0 + s*4, gn = n0 + b_nn;
    rb[s] = (gk < ke && gn < Nn) ? W[(size_t)gk*Nn + gn] : 0.f;
  }

  for (int k0 = ks; k0 < ke; k0 += 16){
    #pragma unroll
    for (int s=0; s<4; s++) As[a_kk][a_mm + s*16] = ra[s];
    #pragma unroll
    for (int s=0; s<4; s++) Bs[b_k0 + s*4][b_nn] = rb[s];
    __syncthreads();
    // prefetch next k-tile while computing this one
    if (k0 + 16 < ke){
      #pragma unroll
      for (int s=0; s<4; s++){
        int gk = k0 + 16 + a_kk;
        ra[s] = (gk < ke) ? A[(size_t)(m0 + a_mm + s*16)*K + gk] : 0.f;
      }
      #pragma unroll
      for (int s=0; s<4; s++){
        int gk = k0 + 16 + b_k0 + s*4, gn = n0 + b_nn;
        rb[s] = (gk < ke && gn < Nn) ? W[(size_t)gk*Nn + gn] : 0.f;
      }
    }
    #pragma unroll
    for (int kk=0; kk<16; kk++){
      float a[4], bv[4];
      #pragma unroll
      for (int i2=0; i2<4; i2++) a[i2] = As[kk][ty*4+i2];
      #pragma unroll
      for (int j2=0; j2<4; j2++) bv[j2] = Bs[kk][tx*4+j2];
      #pragma unroll
      for (int i2=0; i2<4; i2++)
        #pragma unroll
        for (int j2=0; j2<4; j2++) acc[i2][j2] += a[i2]*bv[j2];
    }
    __syncthreads();
  }

  if (ACT == 2){
    float* po = out + (size_t)blockIdx.z*M*Nn;
    #pragma unroll
    for (int j2=0; j2<4; j2++){
      int gn = n0 + tx*4 + j2;
      if (gn < Nn){
        #pragma unroll
        for (int i2=0; i2<4; i2++)
          po[(size_t)(m0 + ty*4 + i2)*Nn + gn] = acc[i2][j2];
      }
    }
  } else {
    #pragma unroll
    for (int j2=0; j2<4; j2++){
      int gn = n0 + tx*4 + j2;
      if (gn < Nn){
        float bb = bias[gn];
        #pragma unroll
        for (int i2=0; i2<4; i2++){
          float v = acc[i2][j2] + bb;
          v = (ACT == 0) ? fmaxf(v, 0.f) : 1.0f/(1.0f + __expf(-v));
          out[(size_t)(m0 + ty*4 + i2)*Nn + gn] = v;
        }
      }
    }
  }
}

// split-K partial reduction + bias + relu
__global__ __launch_bounds__(256)
void reduce_bias_relu(const float* __restrict__ part, const float* __restrict__ bias,
                      float* __restrict__ out, int M, int Nn, int S){
  int idx = blockIdx.x*256 + threadIdx.x;
  if (idx >= M*Nn) return;
  int n = idx % Nn;
  float s = bias[n];
  for (int i=0; i<S; i++) s += part[(size_t)i*M*Nn + idx];
  out[idx] = fmaxf(s, 0.f);
}

// mu/var heads + reparameterize, fused: one thread per (b, zi).
__global__ __launch_bounds__(256)
void latent_kernel(const float* __restrict__ e2,
                   const float* __restrict__ Wmu, const float* __restrict__ bmu,
                   const float* __restrict__ Wvar, const float* __restrict__ bvar,
                   const float* __restrict__ eps, float* __restrict__ z){
  int idx = blockIdx.x*256 + threadIdx.x;   // grid exact: 1024*70 = 280*256
  int b = idx / ZD, zi = idx - b*ZD;
  const float* er = e2 + (size_t)b*HD;
  float amu = 0.f, avr = 0.f;
  for (int j=0; j<HD; j++){
    float e = er[j];
    amu += e*Wmu[j*ZD + zi];
    avr += e*Wvar[j*ZD + zi];
  }
  float mu = amu + bmu[zi];
  float va = avr + bvar[zi];
  float sp = fmaxf(va, 0.f) + log1pf(__expf(-fabsf(va)));   // stable softplus
  z[idx] = mu + eps[idx]*sqrtf(sp + 1e-10f);
}

extern "C" void kernel_launch(void* const* d_in, const int* in_sizes, int n_in,
                              void* d_out, int out_size, void* d_ws, size_t ws_size,
                              hipStream_t stream){
  (void)in_sizes; (void)n_in; (void)out_size; (void)ws_size;
  const float* nodes  = (const float*)d_in[0];
  const float* logits = (const float*)d_in[1];
  const float* gumbel = (const float*)d_in[2];
  const float* eps    = (const float*)d_in[3];
  const float* W1 =(const float*)d_in[4],  *b1 =(const float*)d_in[5];
  const float* W2 =(const float*)d_in[6],  *b2 =(const float*)d_in[7];
  const float* W3 =(const float*)d_in[8],  *b3 =(const float*)d_in[9];
  const float* We1=(const float*)d_in[10], *be1=(const float*)d_in[11];
  const float* We2=(const float*)d_in[12], *be2=(const float*)d_in[13];
  const float* Wmu=(const float*)d_in[14], *bmu=(const float*)d_in[15];
  const float* Wvr=(const float*)d_in[16], *bvr=(const float*)d_in[17];
  const float* Wd1=(const float*)d_in[18], *bd1=(const float*)d_in[19];
  const float* Wd2=(const float*)d_in[20], *bd2=(const float*)d_in[21];
  // edge_src/edge_dst (d_in[22], d_in[23]) unused: grid graph handled analytically.

  char* ws = (char*)d_ws;
  // ws layout (bytes), total ~96 MB:
  bf16*  h3 = (bf16*)(ws);                 // B*N*48*2       = 77,070,336
  float* g  = (float*)(ws + 77070336);     // B*3360*4       = 13,762,560
  float* e1 = (float*)(ws + 90832896);     // B*400*4        =  1,638,400
  float* e2 = (float*)(ws + 92471296);     // B*400*4
  float* zb = (float*)(ws + 94109696);     // B*70*4         =    286,720
  float* dd = (float*)(ws + 94396416);     // B*400*4
  float* part = (float*)(ws);              // 8*1024*400*4 = 13.1 MB, aliases h3 (dead by then)
  float* out = (float*)d_out;

  gcn_fused<<<4096, 256, 0, stream>>>(nodes, W1, b1, W2, b2, W3, b3, h3);
  softmax_einsum_kernel<<<1024, 256, 0, stream>>>(logits, gumbel, h3, g);
  // We1: M=1024, K=3360, N=400, split-K x8 (chunk 432 = 27*16)
  dense_kernel<2><<<dim3(16, 7, 8), 256, 0, stream>>>(g, We1, nullptr, part, 1024, 3360, 400, 432);
  reduce_bias_relu<<<1600, 256, 0, stream>>>(part, be1, e1, 1024, 400, 8);
  dense_kernel<0><<<dim3(16, 7, 1), 256, 0, stream>>>(e1, We2, be2, e2, 1024, 400, 400, 400);
  latent_kernel<<<280, 256, 0, stream>>>(e2, Wmu, bmu, Wvr, bvr, eps, zb);
  dense_kernel<0><<<dim3(16, 7, 1), 256, 0, stream>>>(zb, Wd1, bd1, dd, 1024, 70, 400, 70);
  dense_kernel<1><<<dim3(16, 13, 1), 256, 0, stream>>>(dd, Wd2, bd2, out, 1024, 400, 784, 400);
}

// Round 6
// 486.090 us; speedup vs baseline: 2.4714x; 1.0952x over previous
//
#include <hip/hip_runtime.h>
#include <hip/hip_bf16.h>

// VAE with grid-GCN encoder, MI355X. Round 5: MFMA-based gumbel-softmax einsum
// (per-sample bf16 GEMM with hi/lo-split A for f32-accurate results).

#define BB 1024
#define HG 28
#define NN 784
#define KK 70
#define F3 48
#define HD 400
#define ZD 70
#define IMGD 784

typedef __hip_bfloat16 bf16;
typedef __attribute__((ext_vector_type(8))) short s8v;    // 8 bf16 (4 VGPRs) MFMA A/B frag
typedef __attribute__((ext_vector_type(4))) float f32x4;  // MFMA C/D frag

__device__ __forceinline__ float dinv_ij(int i, int j){
  int deg = 1 + (i>0) + (i<HG-1) + (j>0) + (j<HG-1);   // self-loop + 4-neighborhood
  return rsqrtf((float)deg);
}

__device__ __forceinline__ unsigned pk2(float a, float b){
  union { bf16 h; unsigned short u; } ua, ub;
  ua.h = __float2bfloat16(a); ub.h = __float2bfloat16(b);
  return ((unsigned)ub.u << 16) | ua.u;
}

// Three GCN layers fused. One block per (sample, 7-row slab). Feature-major LDS.
__global__ __launch_bounds__(256)
void gcn_fused(const float* __restrict__ nodes,
               const float* __restrict__ W1, const float* __restrict__ b1,
               const float* __restrict__ W2, const float* __restrict__ b2,
               const float* __restrict__ W3, const float* __restrict__ b3,
               bf16* __restrict__ h3){
  __shared__ float h1s[16][308];   // 11 rows x 28 cols
  __shared__ float h2s[32][252];   // 9 rows x 28 cols
  __shared__ float W1s[2][16], b1s[16];
  __shared__ float W2s[16][32], b2s[32];
  __shared__ float W3s[32][48], b3s[48];
  int tid = threadIdx.x;
  if (tid < 32) W1s[tid>>4][tid&15] = W1[tid];
  for (int t = tid; t < 16*32; t += 256) W2s[t>>5][t&31] = W2[t];
  for (int t = tid; t < 32*48; t += 256) W3s[t/48][t%48] = W3[t];
  if (tid < 16) b1s[tid] = b1[tid];
  if (tid < 32) b2s[tid] = b2[tid];
  if (tid < 48) b3s[tid] = b3[tid];

  int b = blockIdx.x >> 2, s = blockIdx.x & 3;
  int base3 = s*7;           // 7 output rows
  int base2 = base3 - 1;     // 9 rows in h2s
  int base1 = base3 - 2;     // 11 rows in h1s
  const float* nb = nodes + (size_t)b*NN*2;
  __syncthreads();

  // ---- layer 1
  for (int t = tid; t < 308; t += 256){
    int lr = t/28, j = t - lr*28;
    int r = base1 + lr;
    if (r < 0 || r >= HG){
      #pragma unroll
      for (int f=0; f<16; f++) h1s[f][t] = 0.f;
    } else {
      float dn = dinv_ij(r,j);
      float a0 = dn*nb[(r*HG+j)*2+0], a1 = dn*nb[(r*HG+j)*2+1];
      if (r > 0)   { float w=dinv_ij(r-1,j); a0 += w*nb[((r-1)*HG+j)*2]; a1 += w*nb[((r-1)*HG+j)*2+1]; }
      if (r < HG-1){ float w=dinv_ij(r+1,j); a0 += w*nb[((r+1)*HG+j)*2]; a1 += w*nb[((r+1)*HG+j)*2+1]; }
      if (j > 0)   { float w=dinv_ij(r,j-1); a0 += w*nb[(r*HG+j-1)*2];   a1 += w*nb[(r*HG+j-1)*2+1]; }
      if (j < HG-1){ float w=dinv_ij(r,j+1); a0 += w*nb[(r*HG+j+1)*2];   a1 += w*nb[(r*HG+j+1)*2+1]; }
      a0 *= dn; a1 *= dn;
      #pragma unroll
      for (int f=0; f<16; f++)
        h1s[f][t] = fmaxf(a0*W1s[0][f] + a1*W1s[1][f] + b1s[f], 0.f);
    }
  }
  __syncthreads();

  // ---- layer 2
  for (int t = tid; t < 252; t += 256){
    int lr = t/28, j = t - lr*28;
    int r = base2 + lr;
    if (r < 0 || r >= HG){
      #pragma unroll
      for (int f=0; f<32; f++) h2s[f][t] = 0.f;
    } else {
      int ln = (lr+1)*28 + j;
      float dn = dinv_ij(r,j);
      float wu = dinv_ij(r-1,j), wd = dinv_ij(r+1,j);
      float wl = (j>0)    ? dinv_ij(r,j-1) : 0.f;
      float wr = (j<HG-1) ? dinv_ij(r,j+1) : 0.f;
      float agg[16];
      #pragma unroll
      for (int f=0; f<16; f++){
        float v = dn*h1s[f][ln] + wu*h1s[f][ln-28] + wd*h1s[f][ln+28];
        if (j>0)    v += wl*h1s[f][ln-1];
        if (j<HG-1) v += wr*h1s[f][ln+1];
        agg[f] = v*dn;
      }
      #pragma unroll
      for (int fog=0; fog<8; fog++){
        float4 acc = *(const float4*)&b2s[fog*4];
        #pragma unroll
        for (int fi=0; fi<16; fi++){
          float4 w = *(const float4*)&W2s[fi][fog*4];
          float a = agg[fi];
          acc.x += a*w.x; acc.y += a*w.y; acc.z += a*w.z; acc.w += a*w.w;
        }
        h2s[fog*4+0][t] = fmaxf(acc.x, 0.f);
        h2s[fog*4+1][t] = fmaxf(acc.y, 0.f);
        h2s[fog*4+2][t] = fmaxf(acc.z, 0.f);
        h2s[fog*4+3][t] = fmaxf(acc.w, 0.f);
      }
    }
  }
  __syncthreads();

  // ---- layer 3 -> h3 (global, packed bf16)
  for (int t = tid; t < 196; t += 256){
    int lr = t/28, j = t - lr*28;
    int r = base3 + lr;
    int ln = (lr+1)*28 + j;
    float dn = dinv_ij(r,j);
    float wu = dinv_ij(r-1,j), wd = dinv_ij(r+1,j);
    float wl = (j>0)    ? dinv_ij(r,j-1) : 0.f;
    float wr = (j<HG-1) ? dinv_ij(r,j+1) : 0.f;
    float agg[32];
    #pragma unroll
    for (int f=0; f<32; f++){
      float v = dn*h2s[f][ln] + wu*h2s[f][ln-28] + wd*h2s[f][ln+28];
      if (j>0)    v += wl*h2s[f][ln-1];
      if (j<HG-1) v += wr*h2s[f][ln+1];
      agg[f] = v*dn;
    }
    uint2* op = (uint2*)(h3 + ((size_t)b*NN + r*HG + j)*F3);
    #pragma unroll
    for (int fog=0; fog<12; fog++){
      float4 acc = *(const float4*)&b3s[fog*4];
      #pragma unroll
      for (int fi=0; fi<32; fi++){
        float4 w = *(const float4*)&W3s[fi][fog*4];
        float a = agg[fi];
        acc.x += a*w.x; acc.y += a*w.y; acc.z += a*w.z; acc.w += a*w.w;
      }
      uint2 pv;
      pv.x = pk2(fmaxf(acc.x,0.f), fmaxf(acc.y,0.f));
      pv.y = pk2(fmaxf(acc.z,0.f), fmaxf(acc.w,0.f));
      op[fog] = pv;
    }
  }
}

// Fused gumbel-softmax + einsum via MFMA. One block (4 waves) per sample.
// g[b] = samp^T[70x784] @ h3[784x48]; A fed as bf16 hi+lo split (f32-accurate).
// A/B fragments use the SAME lane->k mapping -> result invariant to HW k-order.
// C/D mapping (HW-verified): col=lane&15, row=(lane>>4)*4+reg.
__global__ __launch_bounds__(256, 2)
void einsum_mfma_kernel(const float* __restrict__ logits, const float* __restrict__ gumbel,
                        const bf16* __restrict__ h3, float* __restrict__ g){
  // LDS: region1 (43,520 B) = samp f32[128][72] aliased by {st, stlo} bf16[80][136]
  //      ht bf16[48][136] (13,056 B), cred f32[80][49] (15,680 B). Total 72,256 B.
  __shared__ __align__(16) char smem[72256];
  float* samp = (float*)smem;                   // [128][72]
  short* stp  = (short*)smem;                   // [80][136] bf16 hi
  short* stlo = (short*)(smem + 21760);         // [80][136] bf16 lo
  short* htp  = (short*)(smem + 43520);         // [48][136] bf16
  float* cred = (float*)(smem + 43520 + 13056); // [80][49]

  int b = blockIdx.x;
  int tid = threadIdx.x;
  int l = tid & 63, w = tid >> 6;

  f32x4 acc[5][3];
  #pragma unroll
  for (int mt=0; mt<5; mt++)
    #pragma unroll
    for (int bt=0; bt<3; bt++) acc[mt][bt] = (f32x4){0.f,0.f,0.f,0.f};

  for (int chunk = 0; chunk < 7; chunk++){
    int c0 = chunk*128;
    int nvalid = min(128, NN - c0);
    __syncthreads();   // prev chunk's MFMA reads of st/ht complete

    // ---- stage x = 2*(logits+gumbel) into samp[n][k], coalesced float4
    {
      const float4* l4 = (const float4*)(logits + ((size_t)b*NN + c0)*KK);
      const float4* g4 = (const float4*)(gumbel + ((size_t)b*NN + c0)*KK);
      int lim = nvalid*KK/4;
      for (int t = tid; t < 2240; t += 256){
        if (t < lim){
          float4 lv = l4[t], gv = g4[t];
          float xs[4] = {2.f*(lv.x+gv.x), 2.f*(lv.y+gv.y), 2.f*(lv.z+gv.z), 2.f*(lv.w+gv.w)};
          int e = t*4;
          #pragma unroll
          for (int i2=0;i2<4;i2++){
            int n = (e+i2)/KK, k = (e+i2) - KK*n;
            samp[n*72 + k] = xs[i2];
          }
        }
      }
    }
    // ---- stage h3 transposed -> ht[f][n] (zero for padded nodes)
    {
      int n = tid & 127, fh = tid >> 7;   // fh: 2 groups of 24 features
      bool valid = n < nvalid;
      const uint2* src = (const uint2*)(h3 + ((size_t)b*NN + c0 + n)*F3 + fh*24);
      #pragma unroll
      for (int j=0; j<6; j++){
        uint2 v = valid ? src[j] : (uint2){0u,0u};
        int f0 = fh*24 + j*4;
        htp[(f0+0)*136 + n] = (short)(v.x & 0xFFFFu);
        htp[(f0+1)*136 + n] = (short)(v.x >> 16);
        htp[(f0+2)*136 + n] = (short)(v.y & 0xFFFFu);
        htp[(f0+3)*136 + n] = (short)(v.y >> 16);
      }
    }
    __syncthreads();

    // ---- softmax: 2 threads per node, 35 classes each; results stay in regs
    int nl = tid >> 1, h = tid & 1;
    bool valid = nl < nvalid;
    float p[35];
    if (valid){
      float x[35], m = -1e30f;
      #pragma unroll
      for (int t=0; t<35; t++){ x[t] = samp[nl*72 + h*35 + t]; m = fmaxf(m, x[t]); }
      m = fmaxf(m, __shfl_xor(m, 1));
      float sum = 0.f;
      #pragma unroll
      for (int t=0; t<35; t++){ x[t] = __expf(x[t]-m); sum += x[t]; }
      sum += __shfl_xor(sum, 1);
      float r = 1.0f/sum;
      #pragma unroll
      for (int t=0; t<35; t++) p[t] = x[t]*r;
    } else {
      #pragma unroll
      for (int t=0; t<35; t++) p[t] = 0.f;
    }
    __syncthreads();   // all samp reads done; safe to overwrite with st/stlo

    // ---- write transposed bf16 hi/lo operand
    #pragma unroll
    for (int t=0; t<35; t++){
      int k = h*35 + t;
      bf16 hi = __float2bfloat16(p[t]);
      float lo = p[t] - __bfloat162float(hi);
      *(bf16*)&stp[k*136 + nl]  = hi;
      *(bf16*)&stlo[k*136 + nl] = __float2bfloat16(lo);
    }
    __syncthreads();

    // ---- MFMA: wave w handles K-step (32 nodes) n0 = w*32
    {
      int n0 = w*32 + (l>>4)*8;
      s8v bfr[3];
      #pragma unroll
      for (int bt=0; bt<3; bt++)
        bfr[bt] = *(const s8v*)&htp[(bt*16 + (l&15))*136 + n0];
      #pragma unroll
      for (int mt=0; mt<5; mt++){
        s8v ah = *(const s8v*)&stp[(mt*16 + (l&15))*136 + n0];
        s8v al = *(const s8v*)&stlo[(mt*16 + (l&15))*136 + n0];
        #pragma unroll
        for (int bt=0; bt<3; bt++){
          acc[mt][bt] = __builtin_amdgcn_mfma_f32_16x16x32_bf16(ah, bfr[bt], acc[mt][bt], 0, 0, 0);
          acc[mt][bt] = __builtin_amdgcn_mfma_f32_16x16x32_bf16(al, bfr[bt], acc[mt][bt], 0, 0, 0);
        }
      }
    }
  }

  // ---- cross-wave reduction (C/D layout: col=l&15, row=(l>>4)*4+r)
  __syncthreads();
  for (int rw = 0; rw < 4; rw++){
    if (w == rw){
      #pragma unroll
      for (int mt=0; mt<5; mt++)
        #pragma unroll
        for (int bt=0; bt<3; bt++)
          #pragma unroll
          for (int r=0; r<4; r++){
            int row = mt*16 + (l>>4)*4 + r;
            int col = bt*16 + (l&15);
            if (rw == 0) cred[row*49 + col] = acc[mt][bt][r];
            else         cred[row*49 + col] += acc[mt][bt][r];
          }
    }
    __syncthreads();
  }
  // ---- coalesced store of g[b][70][48]
  for (int t = tid; t < KK*F3; t += 256){
    int r = t / F3, c = t - r*F3;
    g[(size_t)b*(KK*F3) + t] = cred[r*49 + c];
  }
}

// Register-prefetch dense: out = act(A[f32, MxK] @ W[f32, KxN] + b).
template<int ACT>   // 0=relu, 1=sigmoid, 2=partial (no bias/act)
__global__ __launch_bounds__(256)
void dense_kernel(const float* __restrict__ A, const float* __restrict__ W,
                  const float* __restrict__ bias, float* __restrict__ out,
                  int M, int K, int Nn, int kChunk){
  __shared__ float As[16][65];
  __shared__ float Bs[16][64];
  int tx = threadIdx.x & 15, ty = threadIdx.x >> 4;
  int m0 = blockIdx.x*64, n0 = blockIdx.y*64;
  int ks = blockIdx.z * kChunk;
  int ke = min(K, ks + kChunk);
  int a_kk = threadIdx.x & 15, a_mm = threadIdx.x >> 4;
  int b_nn = threadIdx.x & 63, b_k0 = threadIdx.x >> 6;
  float ra[4], rb[4];
  float acc[4][4] = {};

  #pragma unroll
  for (int s=0; s<4; s++){
    int gk = ks + a_kk;
    ra[s] = (gk < ke) ? A[(size_t)(m0 + a_mm + s*16)*K + gk] : 0.f;
  }
  #pragma unroll
  for (int s=0; s<4; s++){
    int gk = ks + b_k0 + s*4, gn = n0 + b_nn;
    rb[s] = (gk < ke && gn < Nn) ? W[(size_t)gk*Nn + gn] : 0.f;
  }

  for (int k0 = ks; k0 < ke; k0 += 16){
    #pragma unroll
    for (int s=0; s<4; s++) As[a_kk][a_mm + s*16] = ra[s];
    #pragma unroll
    for (int s=0; s<4; s++) Bs[b_k0 + s*4][b_nn] = rb[s];
    __syncthreads();
    if (k0 + 16 < ke){
      #pragma unroll
      for (int s=0; s<4; s++){
        int gk = k0 + 16 + a_kk;
        ra[s] = (gk < ke) ? A[(size_t)(m0 + a_mm + s*16)*K + gk] : 0.f;
      }
      #pragma unroll
      for (int s=0; s<4; s++){
        int gk = k0 + 16 + b_k0 + s*4, gn = n0 + b_nn;
        rb[s] = (gk < ke && gn < Nn) ? W[(size_t)gk*Nn + gn] : 0.f;
      }
    }
    #pragma unroll
    for (int kk=0; kk<16; kk++){
      float a[4], bv[4];
      #pragma unroll
      for (int i2=0; i2<4; i2++) a[i2] = As[kk][ty*4+i2];
      #pragma unroll
      for (int j2=0; j2<4; j2++) bv[j2] = Bs[kk][tx*4+j2];
      #pragma unroll
      for (int i2=0; i2<4; i2++)
        #pragma unroll
        for (int j2=0; j2<4; j2++) acc[i2][j2] += a[i2]*bv[j2];
    }
    __syncthreads();
  }

  if (ACT == 2){
    float* po = out + (size_t)blockIdx.z*M*Nn;
    #pragma unroll
    for (int j2=0; j2<4; j2++){
      int gn = n0 + tx*4 + j2;
      if (gn < Nn){
        #pragma unroll
        for (int i2=0; i2<4; i2++)
          po[(size_t)(m0 + ty*4 + i2)*Nn + gn] = acc[i2][j2];
      }
    }
  } else {
    #pragma unroll
    for (int j2=0; j2<4; j2++){
      int gn = n0 + tx*4 + j2;
      if (gn < Nn){
        float bb = bias[gn];
        #pragma unroll
        for (int i2=0; i2<4; i2++){
          float v = acc[i2][j2] + bb;
          v = (ACT == 0) ? fmaxf(v, 0.f) : 1.0f/(1.0f + __expf(-v));
          out[(size_t)(m0 + ty*4 + i2)*Nn + gn] = v;
        }
      }
    }
  }
}

// split-K partial reduction + bias + relu
__global__ __launch_bounds__(256)
void reduce_bias_relu(const float* __restrict__ part, const float* __restrict__ bias,
                      float* __restrict__ out, int M, int Nn, int S){
  int idx = blockIdx.x*256 + threadIdx.x;
  if (idx >= M*Nn) return;
  int n = idx % Nn;
  float s = bias[n];
  for (int i=0; i<S; i++) s += part[(size_t)i*M*Nn + idx];
  out[idx] = fmaxf(s, 0.f);
}

// mu/var heads + reparameterize
__global__ __launch_bounds__(256)
void latent_kernel(const float* __restrict__ e2,
                   const float* __restrict__ Wmu, const float* __restrict__ bmu,
                   const float* __restrict__ Wvar, const float* __restrict__ bvar,
                   const float* __restrict__ eps, float* __restrict__ z){
  int idx = blockIdx.x*256 + threadIdx.x;
  int b = idx / ZD, zi = idx - b*ZD;
  const float* er = e2 + (size_t)b*HD;
  float amu = 0.f, avr = 0.f;
  for (int j=0; j<HD; j++){
    float e = er[j];
    amu += e*Wmu[j*ZD + zi];
    avr += e*Wvar[j*ZD + zi];
  }
  float mu = amu + bmu[zi];
  float va = avr + bvar[zi];
  float sp = fmaxf(va, 0.f) + log1pf(__expf(-fabsf(va)));
  z[idx] = mu + eps[idx]*sqrtf(sp + 1e-10f);
}

extern "C" void kernel_launch(void* const* d_in, const int* in_sizes, int n_in,
                              void* d_out, int out_size, void* d_ws, size_t ws_size,
                              hipStream_t stream){
  (void)in_sizes; (void)n_in; (void)out_size; (void)ws_size;
  const float* nodes  = (const float*)d_in[0];
  const float* logits = (const float*)d_in[1];
  const float* gumbel = (const float*)d_in[2];
  const float* eps    = (const float*)d_in[3];
  const float* W1 =(const float*)d_in[4],  *b1 =(const float*)d_in[5];
  const float* W2 =(const float*)d_in[6],  *b2 =(const float*)d_in[7];
  const float* W3 =(const float*)d_in[8],  *b3 =(const float*)d_in[9];
  const float* We1=(const float*)d_in[10], *be1=(const float*)d_in[11];
  const float* We2=(const float*)d_in[12], *be2=(const float*)d_in[13];
  const float* Wmu=(const float*)d_in[14], *bmu=(const float*)d_in[15];
  const float* Wvr=(const float*)d_in[16], *bvr=(const float*)d_in[17];
  const float* Wd1=(const float*)d_in[18], *bd1=(const float*)d_in[19];
  const float* Wd2=(const float*)d_in[20], *bd2=(const float*)d_in[21];
  // edge_src/edge_dst unused: grid graph handled analytically.

  char* ws = (char*)d_ws;
  bf16*  h3 = (bf16*)(ws);                 // B*N*48*2       = 77,070,336
  float* g  = (float*)(ws + 77070336);     // B*3360*4       = 13,762,560
  float* e1 = (float*)(ws + 90832896);
  float* e2 = (float*)(ws + 92471296);
  float* zb = (float*)(ws + 94109696);
  float* dd = (float*)(ws + 94396416);
  float* part = (float*)(ws);              // aliases h3 (dead by then)
  float* out = (float*)d_out;

  gcn_fused<<<4096, 256, 0, stream>>>(nodes, W1, b1, W2, b2, W3, b3, h3);
  einsum_mfma_kernel<<<1024, 256, 0, stream>>>(logits, gumbel, h3, g);
  dense_kernel<2><<<dim3(16, 7, 8), 256, 0, stream>>>(g, We1, nullptr, part, 1024, 3360, 400, 432);
  reduce_bias_relu<<<1600, 256, 0, stream>>>(part, be1, e1, 1024, 400, 8);
  dense_kernel<0><<<dim3(16, 7, 1), 256, 0, stream>>>(e1, We2, be2, e2, 1024, 400, 400, 400);
  latent_kernel<<<280, 256, 0, stream>>>(e2, Wmu, bmu, Wvr, bvr, eps, zb);
  dense_kernel<0><<<dim3(16, 7, 1), 256, 0, stream>>>(zb, Wd1, bd1, dd, 1024, 70, 400, 70);
  dense_kernel<1><<<dim3(16, 13, 1), 256, 0, stream>>>(dd, Wd2, bd2, out, 1024, 400, 784, 400);
}

// Round 7
// 420.426 us; speedup vs baseline: 2.8574x; 1.1562x over previous
//
#include <hip/hip_runtime.h>
#include <hip/hip_bf16.h>

// VAE with grid-GCN encoder, MI355X. Round 6: gcn_fused restructured as
// phase-split GEMMs (node-major LDS, b128 stencils, register-held weights)
// to kill the DS-pipe broadcast-weight bottleneck.

#define BB 1024
#define HG 28
#define NN 784
#define KK 70
#define F3 48
#define HD 400
#define ZD 70
#define IMGD 784

typedef __hip_bfloat16 bf16;
typedef __attribute__((ext_vector_type(8))) short s8v;    // 8 bf16 (4 VGPRs) MFMA A/B frag
typedef __attribute__((ext_vector_type(4))) float f32x4;  // MFMA C/D frag

__device__ __forceinline__ float dinv_ij(int i, int j){
  int deg = 1 + (i>0) + (i<HG-1) + (j>0) + (j<HG-1);   // self-loop + 4-neighborhood
  return rsqrtf((float)deg);
}

__device__ __forceinline__ unsigned pk2(float a, float b){
  union { bf16 h; unsigned short u; } ua, ub;
  ua.h = __float2bfloat16(a); ub.h = __float2bfloat16(b);
  return ((unsigned)ub.u << 16) | ua.u;
}

// Three GCN layers fused, one block per (sample, 7-row slab).
// Phases: L1 -> agg1 -> L2-GEMM -> agg2 -> L3-GEMM -> copyout.
// LDS regions: A [0,36288) {h1s[308][20] / h2s[252][36] / h3buf[196][56]bf16},
//              B [36288,64512) {agg1[252][20] / agg2[196][36]}, weights @64512.
__global__ __launch_bounds__(256, 2)
void gcn_fused(const float* __restrict__ nodes,
               const float* __restrict__ W1, const float* __restrict__ b1,
               const float* __restrict__ W2, const float* __restrict__ b2,
               const float* __restrict__ W3, const float* __restrict__ b3,
               bf16* __restrict__ h3){
  __shared__ __align__(16) char smem[73216];
  float* regA = (float*)smem;
  float* regB = (float*)(smem + 36288);
  float* wbuf = (float*)(smem + 64512);
  float* W1s = wbuf;          float* b1s = wbuf + 32;
  float* W2s = wbuf + 48;     float* b2s = wbuf + 560;
  float* W3s = wbuf + 592;    float* b3s = wbuf + 2128;

  int tid = threadIdx.x;
  if (tid < 32)  W1s[tid] = W1[tid];
  if (tid < 16)  b1s[tid] = b1[tid];
  for (int t = tid; t < 512;  t += 256) W2s[t] = W2[t];
  if (tid < 32)  b2s[tid] = b2[tid];
  for (int t = tid; t < 1536; t += 256) W3s[t] = W3[t];
  if (tid < 48)  b3s[tid] = b3[tid];

  int b = blockIdx.x >> 2, s = blockIdx.x & 3;
  int base3 = s*7;           // 7 output rows
  int base2 = base3 - 1;     // 9 rows (252 nodes) of h2/agg1
  int base1 = base3 - 2;     // 11 rows (308 nodes) of h1
  const float* nb = nodes + (size_t)b*NN*2;
  __syncthreads();

  // ---- P1: layer 1, nodes(global) -> h1s[308][20] node-major
  {
    float* h1s = regA;
    for (int t = tid; t < 308; t += 256){
      int lr = t/28, j = t - lr*28;
      int r = base1 + lr;
      float o[16] __attribute__((aligned(16)));
      if (r < 0 || r >= HG){
        #pragma unroll
        for (int f=0; f<16; f++) o[f] = 0.f;
      } else {
        float dn = dinv_ij(r,j);
        float a0 = dn*nb[(r*HG+j)*2+0], a1 = dn*nb[(r*HG+j)*2+1];
        if (r > 0)   { float w=dinv_ij(r-1,j); a0 += w*nb[((r-1)*HG+j)*2]; a1 += w*nb[((r-1)*HG+j)*2+1]; }
        if (r < HG-1){ float w=dinv_ij(r+1,j); a0 += w*nb[((r+1)*HG+j)*2]; a1 += w*nb[((r+1)*HG+j)*2+1]; }
        if (j > 0)   { float w=dinv_ij(r,j-1); a0 += w*nb[(r*HG+j-1)*2];   a1 += w*nb[(r*HG+j-1)*2+1]; }
        if (j < HG-1){ float w=dinv_ij(r,j+1); a0 += w*nb[(r*HG+j+1)*2];   a1 += w*nb[(r*HG+j+1)*2+1]; }
        a0 *= dn; a1 *= dn;
        #pragma unroll
        for (int f=0; f<16; f++) o[f] = fmaxf(a0*W1s[f] + a1*W1s[16+f] + b1s[f], 0.f);
      }
      float* dst = h1s + t*20;
      #pragma unroll
      for (int q=0; q<4; q++) *(float4*)(dst + 4*q) = *(float4*)&o[4*q];
    }
  }
  __syncthreads();

  // ---- P2: agg1[252][20] = sym-norm aggregate of h1s
  if (tid < 252){
    const float* h1s = regA;
    float* agg1 = regB;
    int lr = tid/28, j = tid - lr*28;
    int r = base2 + lr;
    float o[16] __attribute__((aligned(16)));
    if (r < 0 || r >= HG){
      #pragma unroll
      for (int f=0; f<16; f++) o[f] = 0.f;
    } else {
      int ln = (lr+1)*28 + j;            // h1s slot of (r,j)
      float dn = dinv_ij(r,j);
      float wu = dinv_ij(r-1,j), wd = dinv_ij(r+1,j);
      float wl = (j>0)    ? dinv_ij(r,j-1) : 0.f;
      float wr = (j<HG-1) ? dinv_ij(r,j+1) : 0.f;
      const float* pc = h1s + ln*20;
      #pragma unroll
      for (int q=0; q<4; q++){
        float4 vc = *(const float4*)(pc + 4*q);
        float4 vu = *(const float4*)(pc - 28*20 + 4*q);
        float4 vd = *(const float4*)(pc + 28*20 + 4*q);
        float4 vl = *(const float4*)(pc - 20 + 4*q);
        float4 vr = *(const float4*)(pc + 20 + 4*q);
        o[4*q+0] = dn*(dn*vc.x + wu*vu.x + wd*vd.x + wl*vl.x + wr*vr.x);
        o[4*q+1] = dn*(dn*vc.y + wu*vu.y + wd*vd.y + wl*vl.y + wr*vr.y);
        o[4*q+2] = dn*(dn*vc.z + wu*vu.z + wd*vd.z + wl*vl.z + wr*vr.z);
        o[4*q+3] = dn*(dn*vc.w + wu*vu.w + wd*vd.w + wl*vl.w + wr*vr.w);
      }
    }
    float* dst = agg1 + tid*20;
    #pragma unroll
    for (int q=0; q<4; q++) *(float4*)(dst + 4*q) = *(float4*)&o[4*q];
  }
  __syncthreads();

  // ---- P3: L2-GEMM  h2s[252][36] = relu(agg1[252][16] @ W2[16][32] + b2)
  // thread (tx=tid&7 -> 4 cols, ty=tid>>3 -> nodes ty+32i), W2 block in regs.
  {
    const float* agg1 = regB;
    float* h2s = regA;                   // h1s dead
    int tx = tid & 7, ty = tid >> 3;
    float4 w2r[16];
    #pragma unroll
    for (int fi=0; fi<16; fi++) w2r[fi] = *(const float4*)&W2s[fi*32 + tx*4];
    float4 bb = *(const float4*)&b2s[tx*4];
    #pragma unroll
    for (int i=0; i<8; i++){
      int n = ty + 32*i;
      if (n < 252){
        float af[16] __attribute__((aligned(16)));
        const float* ap = agg1 + n*20;
        #pragma unroll
        for (int q=0; q<4; q++) *(float4*)&af[4*q] = *(const float4*)(ap + 4*q);
        float4 acc = bb;
        #pragma unroll
        for (int fi=0; fi<16; fi++){
          float a = af[fi];
          acc.x += a*w2r[fi].x; acc.y += a*w2r[fi].y;
          acc.z += a*w2r[fi].z; acc.w += a*w2r[fi].w;
        }
        acc.x = fmaxf(acc.x,0.f); acc.y = fmaxf(acc.y,0.f);
        acc.z = fmaxf(acc.z,0.f); acc.w = fmaxf(acc.w,0.f);
        *(float4*)&h2s[n*36 + tx*4] = acc;
      }
    }
  }
  __syncthreads();

  // ---- P4: agg2[196][36] = sym-norm aggregate of h2s
  if (tid < 196){
    const float* h2s = regA;
    float* agg2 = regB;                  // agg1 dead
    int lr = tid/28, j = tid - lr*28;
    int r = base3 + lr;                  // always in-grid
    int ln = (lr+1)*28 + j;
    float dn = dinv_ij(r,j);
    float wu = dinv_ij(r-1,j), wd = dinv_ij(r+1,j);
    float wl = (j>0)    ? dinv_ij(r,j-1) : 0.f;
    float wr = (j<HG-1) ? dinv_ij(r,j+1) : 0.f;
    const float* pc = h2s + ln*36;
    float* dst = agg2 + tid*36;
    #pragma unroll
    for (int q=0; q<8; q++){
      float4 vc = *(const float4*)(pc + 4*q);
      float4 vu = *(const float4*)(pc - 28*36 + 4*q);
      float4 vd = *(const float4*)(pc + 28*36 + 4*q);
      float4 vl = *(const float4*)(pc - 36 + 4*q);
      float4 vr = *(const float4*)(pc + 36 + 4*q);
      float4 o;
      o.x = dn*(dn*vc.x + wu*vu.x + wd*vd.x + wl*vl.x + wr*vr.x);
      o.y = dn*(dn*vc.y + wu*vu.y + wd*vd.y + wl*vl.y + wr*vr.y);
      o.z = dn*(dn*vc.z + wu*vu.z + wd*vd.z + wl*vl.z + wr*vr.z);
      o.w = dn*(dn*vc.w + wu*vu.w + wd*vd.w + wl*vl.w + wr*vr.w);
      *(float4*)(dst + 4*q) = o;
    }
  }
  __syncthreads();

  // ---- P5: L3-GEMM  h3buf[196][56]bf16 = relu(agg2[196][32] @ W3[32][48] + b3)
  // thread (tx=tid%12 -> 4 cols, ty=tid/12 -> nodes ty+21i), W3 block in regs.
  {
    bf16* h3buf = (bf16*)regA;           // h2s dead
    if (tid < 252){
      const float* agg2 = regB;
      int tx = tid % 12, ty = tid / 12;
      float4 w3r[32];
      #pragma unroll
      for (int fi=0; fi<32; fi++) w3r[fi] = *(const float4*)&W3s[fi*48 + tx*4];
      float4 bb = *(const float4*)&b3s[tx*4];
      #pragma unroll
      for (int i=0; i<10; i++){
        int n = ty + 21*i;
        if (n < 196){
          float af[32] __attribute__((aligned(16)));
          const float* ap = agg2 + n*36;
          #pragma unroll
          for (int q=0; q<8; q++) *(float4*)&af[4*q] = *(const float4*)(ap + 4*q);
          float4 acc = bb;
          #pragma unroll
          for (int fi=0; fi<32; fi++){
            float a = af[fi];
            acc.x += a*w3r[fi].x; acc.y += a*w3r[fi].y;
            acc.z += a*w3r[fi].z; acc.w += a*w3r[fi].w;
          }
          uint2 pv;
          pv.x = pk2(fmaxf(acc.x,0.f), fmaxf(acc.y,0.f));
          pv.y = pk2(fmaxf(acc.z,0.f), fmaxf(acc.w,0.f));
          *(uint2*)((char*)h3buf + n*112 + tx*8) = pv;
        }
      }
    }
  }
  __syncthreads();

  // ---- P6: coalesced copyout h3buf -> h3 (196*48 bf16 contiguous)
  {
    const char* h3buf = (const char*)regA;
    uint4* dst = (uint4*)(h3 + ((size_t)b*NN + base3*28)*F3);
    for (int t = tid; t < 1176; t += 256){
      int n = t/6, gq = t - n*6;
      dst[t] = *(const uint4*)(h3buf + n*112 + gq*16);
    }
  }
}

// Fused gumbel-softmax + einsum via MFMA. One block (4 waves) per sample.
// g[b] = samp^T[70x784] @ h3[784x48]; A fed as bf16 hi+lo split (f32-accurate).
__global__ __launch_bounds__(256, 2)
void einsum_mfma_kernel(const float* __restrict__ logits, const float* __restrict__ gumbel,
                        const bf16* __restrict__ h3, float* __restrict__ g){
  __shared__ __align__(16) char smem[72256];
  float* samp = (float*)smem;                   // [128][72]
  short* stp  = (short*)smem;                   // [80][136] bf16 hi
  short* stlo = (short*)(smem + 21760);         // [80][136] bf16 lo
  short* htp  = (short*)(smem + 43520);         // [48][136] bf16
  float* cred = (float*)(smem + 43520 + 13056); // [80][49]

  int b = blockIdx.x;
  int tid = threadIdx.x;
  int l = tid & 63, w = tid >> 6;

  f32x4 acc[5][3];
  #pragma unroll
  for (int mt=0; mt<5; mt++)
    #pragma unroll
    for (int bt=0; bt<3; bt++) acc[mt][bt] = (f32x4){0.f,0.f,0.f,0.f};

  for (int chunk = 0; chunk < 7; chunk++){
    int c0 = chunk*128;
    int nvalid = min(128, NN - c0);
    __syncthreads();

    {
      const float4* l4 = (const float4*)(logits + ((size_t)b*NN + c0)*KK);
      const float4* g4 = (const float4*)(gumbel + ((size_t)b*NN + c0)*KK);
      int lim = nvalid*KK/4;
      for (int t = tid; t < 2240; t += 256){
        if (t < lim){
          float4 lv = l4[t], gv = g4[t];
          float xs[4] = {2.f*(lv.x+gv.x), 2.f*(lv.y+gv.y), 2.f*(lv.z+gv.z), 2.f*(lv.w+gv.w)};
          int e = t*4;
          #pragma unroll
          for (int i2=0;i2<4;i2++){
            int n = (e+i2)/KK, k = (e+i2) - KK*n;
            samp[n*72 + k] = xs[i2];
          }
        }
      }
    }
    {
      int n = tid & 127, fh = tid >> 7;
      bool valid = n < nvalid;
      const uint2* src = (const uint2*)(h3 + ((size_t)b*NN + c0 + n)*F3 + fh*24);
      #pragma unroll
      for (int j=0; j<6; j++){
        uint2 v = valid ? src[j] : (uint2){0u,0u};
        int f0 = fh*24 + j*4;
        htp[(f0+0)*136 + n] = (short)(v.x & 0xFFFFu);
        htp[(f0+1)*136 + n] = (short)(v.x >> 16);
        htp[(f0+2)*136 + n] = (short)(v.y & 0xFFFFu);
        htp[(f0+3)*136 + n] = (short)(v.y >> 16);
      }
    }
    __syncthreads();

    int nl = tid >> 1, h = tid & 1;
    bool valid = nl < nvalid;
    float p[35];
    if (valid){
      float x[35], m = -1e30f;
      #pragma unroll
      for (int t=0; t<35; t++){ x[t] = samp[nl*72 + h*35 + t]; m = fmaxf(m, x[t]); }
      m = fmaxf(m, __shfl_xor(m, 1));
      float sum = 0.f;
      #pragma unroll
      for (int t=0; t<35; t++){ x[t] = __expf(x[t]-m); sum += x[t]; }
      sum += __shfl_xor(sum, 1);
      float r = 1.0f/sum;
      #pragma unroll
      for (int t=0; t<35; t++) p[t] = x[t]*r;
    } else {
      #pragma unroll
      for (int t=0; t<35; t++) p[t] = 0.f;
    }
    __syncthreads();

    #pragma unroll
    for (int t=0; t<35; t++){
      int k = h*35 + t;
      bf16 hi = __float2bfloat16(p[t]);
      float lo = p[t] - __bfloat162float(hi);
      *(bf16*)&stp[k*136 + nl]  = hi;
      *(bf16*)&stlo[k*136 + nl] = __float2bfloat16(lo);
    }
    __syncthreads();

    {
      int n0 = w*32 + (l>>4)*8;
      s8v bfr[3];
      #pragma unroll
      for (int bt=0; bt<3; bt++)
        bfr[bt] = *(const s8v*)&htp[(bt*16 + (l&15))*136 + n0];
      #pragma unroll
      for (int mt=0; mt<5; mt++){
        s8v ah = *(const s8v*)&stp[(mt*16 + (l&15))*136 + n0];
        s8v al = *(const s8v*)&stlo[(mt*16 + (l&15))*136 + n0];
        #pragma unroll
        for (int bt=0; bt<3; bt++){
          acc[mt][bt] = __builtin_amdgcn_mfma_f32_16x16x32_bf16(ah, bfr[bt], acc[mt][bt], 0, 0, 0);
          acc[mt][bt] = __builtin_amdgcn_mfma_f32_16x16x32_bf16(al, bfr[bt], acc[mt][bt], 0, 0, 0);
        }
      }
    }
  }

  __syncthreads();
  for (int rw = 0; rw < 4; rw++){
    if (w == rw){
      #pragma unroll
      for (int mt=0; mt<5; mt++)
        #pragma unroll
        for (int bt=0; bt<3; bt++)
          #pragma unroll
          for (int r=0; r<4; r++){
            int row = mt*16 + (l>>4)*4 + r;
            int col = bt*16 + (l&15);
            if (rw == 0) cred[row*49 + col] = acc[mt][bt][r];
            else         cred[row*49 + col] += acc[mt][bt][r];
          }
    }
    __syncthreads();
  }
  for (int t = tid; t < KK*F3; t += 256){
    int r = t / F3, c = t - r*F3;
    g[(size_t)b*(KK*F3) + t] = cred[r*49 + c];
  }
}

// Register-prefetch dense: out = act(A[f32, MxK] @ W[f32, KxN] + b).
template<int ACT>   // 0=relu, 1=sigmoid, 2=partial (no bias/act)
__global__ __launch_bounds__(256)
void dense_kernel(const float* __restrict__ A, const float* __restrict__ W,
                  const float* __restrict__ bias, float* __restrict__ out,
                  int M, int K, int Nn, int kChunk){
  __shared__ float As[16][65];
  __shared__ float Bs[16][64];
  int tx = threadIdx.x & 15, ty = threadIdx.x >> 4;
  int m0 = blockIdx.x*64, n0 = blockIdx.y*64;
  int ks = blockIdx.z * kChunk;
  int ke = min(K, ks + kChunk);
  int a_kk = threadIdx.x & 15, a_mm = threadIdx.x >> 4;
  int b_nn = threadIdx.x & 63, b_k0 = threadIdx.x >> 6;
  float ra[4], rb[4];
  float acc[4][4] = {};

  #pragma unroll
  for (int s=0; s<4; s++){
    int gk = ks + a_kk;
    ra[s] = (gk < ke) ? A[(size_t)(m0 + a_mm + s*16)*K + gk] : 0.f;
  }
  #pragma unroll
  for (int s=0; s<4; s++){
    int gk = ks + b_k0 + s*4, gn = n0 + b_nn;
    rb[s] = (gk < ke && gn < Nn) ? W[(size_t)gk*Nn + gn] : 0.f;
  }

  for (int k0 = ks; k0 < ke; k0 += 16){
    #pragma unroll
    for (int s=0; s<4; s++) As[a_kk][a_mm + s*16] = ra[s];
    #pragma unroll
    for (int s=0; s<4; s++) Bs[b_k0 + s*4][b_nn] = rb[s];
    __syncthreads();
    if (k0 + 16 < ke){
      #pragma unroll
      for (int s=0; s<4; s++){
        int gk = k0 + 16 + a_kk;
        ra[s] = (gk < ke) ? A[(size_t)(m0 + a_mm + s*16)*K + gk] : 0.f;
      }
      #pragma unroll
      for (int s=0; s<4; s++){
        int gk = k0 + 16 + b_k0 + s*4, gn = n0 + b_nn;
        rb[s] = (gk < ke && gn < Nn) ? W[(size_t)gk*Nn + gn] : 0.f;
      }
    }
    #pragma unroll
    for (int kk=0; kk<16; kk++){
      float a[4], bv[4];
      #pragma unroll
      for (int i2=0; i2<4; i2++) a[i2] = As[kk][ty*4+i2];
      #pragma unroll
      for (int j2=0; j2<4; j2++) bv[j2] = Bs[kk][tx*4+j2];
      #pragma unroll
      for (int i2=0; i2<4; i2++)
        #pragma unroll
        for (int j2=0; j2<4; j2++) acc[i2][j2] += a[i2]*bv[j2];
    }
    __syncthreads();
  }

  if (ACT == 2){
    float* po = out + (size_t)blockIdx.z*M*Nn;
    #pragma unroll
    for (int j2=0; j2<4; j2++){
      int gn = n0 + tx*4 + j2;
      if (gn < Nn){
        #pragma unroll
        for (int i2=0; i2<4; i2++)
          po[(size_t)(m0 + ty*4 + i2)*Nn + gn] = acc[i2][j2];
      }
    }
  } else {
    #pragma unroll
    for (int j2=0; j2<4; j2++){
      int gn = n0 + tx*4 + j2;
      if (gn < Nn){
        float bb = bias[gn];
        #pragma unroll
        for (int i2=0; i2<4; i2++){
          float v = acc[i2][j2] + bb;
          v = (ACT == 0) ? fmaxf(v, 0.f) : 1.0f/(1.0f + __expf(-v));
          out[(size_t)(m0 + ty*4 + i2)*Nn + gn] = v;
        }
      }
    }
  }
}

// split-K partial reduction + bias + relu
__global__ __launch_bounds__(256)
void reduce_bias_relu(const float* __restrict__ part, const float* __restrict__ bias,
                      float* __restrict__ out, int M, int Nn, int S){
  int idx = blockIdx.x*256 + threadIdx.x;
  if (idx >= M*Nn) return;
  int n = idx % Nn;
  float s = bias[n];
  for (int i=0; i<S; i++) s += part[(size_t)i*M*Nn + idx];
  out[idx] = fmaxf(s, 0.f);
}

// mu/var heads + reparameterize
__global__ __launch_bounds__(256)
void latent_kernel(const float* __restrict__ e2,
                   const float* __restrict__ Wmu, const float* __restrict__ bmu,
                   const float* __restrict__ Wvar, const float* __restrict__ bvar,
                   const float* __restrict__ eps, float* __restrict__ z){
  int idx = blockIdx.x*256 + threadIdx.x;
  int b = idx / ZD, zi = idx - b*ZD;
  const float* er = e2 + (size_t)b*HD;
  float amu = 0.f, avr = 0.f;
  for (int j=0; j<HD; j++){
    float e = er[j];
    amu += e*Wmu[j*ZD + zi];
    avr += e*Wvar[j*ZD + zi];
  }
  float mu = amu + bmu[zi];
  float va = avr + bvar[zi];
  float sp = fmaxf(va, 0.f) + log1pf(__expf(-fabsf(va)));
  z[idx] = mu + eps[idx]*sqrtf(sp + 1e-10f);
}

extern "C" void kernel_launch(void* const* d_in, const int* in_sizes, int n_in,
                              void* d_out, int out_size, void* d_ws, size_t ws_size,
                              hipStream_t stream){
  (void)in_sizes; (void)n_in; (void)out_size; (void)ws_size;
  const float* nodes  = (const float*)d_in[0];
  const float* logits = (const float*)d_in[1];
  const float* gumbel = (const float*)d_in[2];
  const float* eps    = (const float*)d_in[3];
  const float* W1 =(const float*)d_in[4],  *b1 =(const float*)d_in[5];
  const float* W2 =(const float*)d_in[6],  *b2 =(const float*)d_in[7];
  const float* W3 =(const float*)d_in[8],  *b3 =(const float*)d_in[9];
  const float* We1=(const float*)d_in[10], *be1=(const float*)d_in[11];
  const float* We2=(const float*)d_in[12], *be2=(const float*)d_in[13];
  const float* Wmu=(const float*)d_in[14], *bmu=(const float*)d_in[15];
  const float* Wvr=(const float*)d_in[16], *bvr=(const float*)d_in[17];
  const float* Wd1=(const float*)d_in[18], *bd1=(const float*)d_in[19];
  const float* Wd2=(const float*)d_in[20], *bd2=(const float*)d_in[21];
  // edge_src/edge_dst unused: grid graph handled analytically.

  char* ws = (char*)d_ws;
  bf16*  h3 = (bf16*)(ws);                 // B*N*48*2       = 77,070,336
  float* g  = (float*)(ws + 77070336);     // B*3360*4       = 13,762,560
  float* e1 = (float*)(ws + 90832896);
  float* e2 = (float*)(ws + 92471296);
  float* zb = (float*)(ws + 94109696);
  float* dd = (float*)(ws + 94396416);
  float* part = (float*)(ws);              // aliases h3 (dead by then)
  float* out = (float*)d_out;

  gcn_fused<<<4096, 256, 0, stream>>>(nodes, W1, b1, W2, b2, W3, b3, h3);
  einsum_mfma_kernel<<<1024, 256, 0, stream>>>(logits, gumbel, h3, g);
  dense_kernel<2><<<dim3(16, 7, 8), 256, 0, stream>>>(g, We1, nullptr, part, 1024, 3360, 400, 432);
  reduce_bias_relu<<<1600, 256, 0, stream>>>(part, be1, e1, 1024, 400, 8);
  dense_kernel<0><<<dim3(16, 7, 1), 256, 0, stream>>>(e1, We2, be2, e2, 1024, 400, 400, 400);
  latent_kernel<<<280, 256, 0, stream>>>(e2, Wmu, bmu, Wvr, bvr, eps, zb);
  dense_kernel<0><<<dim3(16, 7, 1), 256, 0, stream>>>(zb, Wd1, bd1, dd, 1024, 70, 400, 70);
  dense_kernel<1><<<dim3(16, 13, 1), 256, 0, stream>>>(dd, Wd2, bd2, out, 1024, 400, 784, 400);
}

// Round 8
// 419.153 us; speedup vs baseline: 2.8661x; 1.0030x over previous
//
#include <hip/hip_runtime.h>
#include <hip/hip_bf16.h>

// VAE with grid-GCN encoder, MI355X. Round 7: einsum pipelined (64-node chunks,
// load-under-MFMA, 47.9KB LDS -> 3 blocks/CU, conflict-balanced layouts).

#define BB 1024
#define HG 28
#define NN 784
#define KK 70
#define F3 48
#define HD 400
#define ZD 70
#define IMGD 784

typedef __hip_bfloat16 bf16;
typedef __attribute__((ext_vector_type(8))) short s8v;    // 8 bf16 (4 VGPRs) MFMA A/B frag
typedef __attribute__((ext_vector_type(4))) float f32x4;  // MFMA C/D frag

__device__ __forceinline__ float dinv_ij(int i, int j){
  int deg = 1 + (i>0) + (i<HG-1) + (j>0) + (j<HG-1);   // self-loop + 4-neighborhood
  return rsqrtf((float)deg);
}

__device__ __forceinline__ unsigned pk2(float a, float b){
  union { bf16 h; unsigned short u; } ua, ub;
  ua.h = __float2bfloat16(a); ub.h = __float2bfloat16(b);
  return ((unsigned)ub.u << 16) | ua.u;
}

__device__ __forceinline__ short bfbits(float v){
  union { bf16 h; short s; } u; u.h = __float2bfloat16(v); return u.s;
}

// Three GCN layers fused, one block per (sample, 7-row slab). (unchanged r6)
__global__ __launch_bounds__(256, 2)
void gcn_fused(const float* __restrict__ nodes,
               const float* __restrict__ W1, const float* __restrict__ b1,
               const float* __restrict__ W2, const float* __restrict__ b2,
               const float* __restrict__ W3, const float* __restrict__ b3,
               bf16* __restrict__ h3){
  __shared__ __align__(16) char smem[73216];
  float* regA = (float*)smem;
  float* regB = (float*)(smem + 36288);
  float* wbuf = (float*)(smem + 64512);
  float* W1s = wbuf;          float* b1s = wbuf + 32;
  float* W2s = wbuf + 48;     float* b2s = wbuf + 560;
  float* W3s = wbuf + 592;    float* b3s = wbuf + 2128;

  int tid = threadIdx.x;
  if (tid < 32)  W1s[tid] = W1[tid];
  if (tid < 16)  b1s[tid] = b1[tid];
  for (int t = tid; t < 512;  t += 256) W2s[t] = W2[t];
  if (tid < 32)  b2s[tid] = b2[tid];
  for (int t = tid; t < 1536; t += 256) W3s[t] = W3[t];
  if (tid < 48)  b3s[tid] = b3[tid];

  int b = blockIdx.x >> 2, s = blockIdx.x & 3;
  int base3 = s*7;
  int base2 = base3 - 1;
  int base1 = base3 - 2;
  const float* nb = nodes + (size_t)b*NN*2;
  __syncthreads();

  {
    float* h1s = regA;
    for (int t = tid; t < 308; t += 256){
      int lr = t/28, j = t - lr*28;
      int r = base1 + lr;
      float o[16] __attribute__((aligned(16)));
      if (r < 0 || r >= HG){
        #pragma unroll
        for (int f=0; f<16; f++) o[f] = 0.f;
      } else {
        float dn = dinv_ij(r,j);
        float a0 = dn*nb[(r*HG+j)*2+0], a1 = dn*nb[(r*HG+j)*2+1];
        if (r > 0)   { float w=dinv_ij(r-1,j); a0 += w*nb[((r-1)*HG+j)*2]; a1 += w*nb[((r-1)*HG+j)*2+1]; }
        if (r < HG-1){ float w=dinv_ij(r+1,j); a0 += w*nb[((r+1)*HG+j)*2]; a1 += w*nb[((r+1)*HG+j)*2+1]; }
        if (j > 0)   { float w=dinv_ij(r,j-1); a0 += w*nb[(r*HG+j-1)*2];   a1 += w*nb[(r*HG+j-1)*2+1]; }
        if (j < HG-1){ float w=dinv_ij(r,j+1); a0 += w*nb[(r*HG+j+1)*2];   a1 += w*nb[(r*HG+j+1)*2+1]; }
        a0 *= dn; a1 *= dn;
        #pragma unroll
        for (int f=0; f<16; f++) o[f] = fmaxf(a0*W1s[f] + a1*W1s[16+f] + b1s[f], 0.f);
      }
      float* dst = h1s + t*20;
      #pragma unroll
      for (int q=0; q<4; q++) *(float4*)(dst + 4*q) = *(float4*)&o[4*q];
    }
  }
  __syncthreads();

  if (tid < 252){
    const float* h1s = regA;
    float* agg1 = regB;
    int lr = tid/28, j = tid - lr*28;
    int r = base2 + lr;
    float o[16] __attribute__((aligned(16)));
    if (r < 0 || r >= HG){
      #pragma unroll
      for (int f=0; f<16; f++) o[f] = 0.f;
    } else {
      int ln = (lr+1)*28 + j;
      float dn = dinv_ij(r,j);
      float wu = dinv_ij(r-1,j), wd = dinv_ij(r+1,j);
      float wl = (j>0)    ? dinv_ij(r,j-1) : 0.f;
      float wr = (j<HG-1) ? dinv_ij(r,j+1) : 0.f;
      const float* pc = h1s + ln*20;
      #pragma unroll
      for (int q=0; q<4; q++){
        float4 vc = *(const float4*)(pc + 4*q);
        float4 vu = *(const float4*)(pc - 28*20 + 4*q);
        float4 vd = *(const float4*)(pc + 28*20 + 4*q);
        float4 vl = *(const float4*)(pc - 20 + 4*q);
        float4 vr = *(const float4*)(pc + 20 + 4*q);
        o[4*q+0] = dn*(dn*vc.x + wu*vu.x + wd*vd.x + wl*vl.x + wr*vr.x);
        o[4*q+1] = dn*(dn*vc.y + wu*vu.y + wd*vd.y + wl*vl.y + wr*vr.y);
        o[4*q+2] = dn*(dn*vc.z + wu*vu.z + wd*vd.z + wl*vl.z + wr*vr.z);
        o[4*q+3] = dn*(dn*vc.w + wu*vu.w + wd*vd.w + wl*vl.w + wr*vr.w);
      }
    }
    float* dst = agg1 + tid*20;
    #pragma unroll
    for (int q=0; q<4; q++) *(float4*)(dst + 4*q) = *(float4*)&o[4*q];
  }
  __syncthreads();

  {
    const float* agg1 = regB;
    float* h2s = regA;
    int tx = tid & 7, ty = tid >> 3;
    float4 w2r[16];
    #pragma unroll
    for (int fi=0; fi<16; fi++) w2r[fi] = *(const float4*)&W2s[fi*32 + tx*4];
    float4 bb = *(const float4*)&b2s[tx*4];
    #pragma unroll
    for (int i=0; i<8; i++){
      int n = ty + 32*i;
      if (n < 252){
        float af[16] __attribute__((aligned(16)));
        const float* ap = agg1 + n*20;
        #pragma unroll
        for (int q=0; q<4; q++) *(float4*)&af[4*q] = *(const float4*)(ap + 4*q);
        float4 acc = bb;
        #pragma unroll
        for (int fi=0; fi<16; fi++){
          float a = af[fi];
          acc.x += a*w2r[fi].x; acc.y += a*w2r[fi].y;
          acc.z += a*w2r[fi].z; acc.w += a*w2r[fi].w;
        }
        acc.x = fmaxf(acc.x,0.f); acc.y = fmaxf(acc.y,0.f);
        acc.z = fmaxf(acc.z,0.f); acc.w = fmaxf(acc.w,0.f);
        *(float4*)&h2s[n*36 + tx*4] = acc;
      }
    }
  }
  __syncthreads();

  if (tid < 196){
    const float* h2s = regA;
    float* agg2 = regB;
    int lr = tid/28, j = tid - lr*28;
    int r = base3 + lr;
    int ln = (lr+1)*28 + j;
    float dn = dinv_ij(r,j);
    float wu = dinv_ij(r-1,j), wd = dinv_ij(r+1,j);
    float wl = (j>0)    ? dinv_ij(r,j-1) : 0.f;
    float wr = (j<HG-1) ? dinv_ij(r,j+1) : 0.f;
    const float* pc = h2s + ln*36;
    float* dst = agg2 + tid*36;
    #pragma unroll
    for (int q=0; q<8; q++){
      float4 vc = *(const float4*)(pc + 4*q);
      float4 vu = *(const float4*)(pc - 28*36 + 4*q);
      float4 vd = *(const float4*)(pc + 28*36 + 4*q);
      float4 vl = *(const float4*)(pc - 36 + 4*q);
      float4 vr = *(const float4*)(pc + 36 + 4*q);
      float4 o;
      o.x = dn*(dn*vc.x + wu*vu.x + wd*vd.x + wl*vl.x + wr*vr.x);
      o.y = dn*(dn*vc.y + wu*vu.y + wd*vd.y + wl*vl.y + wr*vr.y);
      o.z = dn*(dn*vc.z + wu*vu.z + wd*vd.z + wl*vl.z + wr*vr.z);
      o.w = dn*(dn*vc.w + wu*vu.w + wd*vd.w + wl*vl.w + wr*vr.w);
      *(float4*)(dst + 4*q) = o;
    }
  }
  __syncthreads();

  {
    bf16* h3buf = (bf16*)regA;
    if (tid < 252){
      const float* agg2 = regB;
      int tx = tid % 12, ty = tid / 12;
      float4 w3r[32];
      #pragma unroll
      for (int fi=0; fi<32; fi++) w3r[fi] = *(const float4*)&W3s[fi*48 + tx*4];
      float4 bb = *(const float4*)&b3s[tx*4];
      #pragma unroll
      for (int i=0; i<10; i++){
        int n = ty + 21*i;
        if (n < 196){
          float af[32] __attribute__((aligned(16)));
          const float* ap = agg2 + n*36;
          #pragma unroll
          for (int q=0; q<8; q++) *(float4*)&af[4*q] = *(const float4*)(ap + 4*q);
          float4 acc = bb;
          #pragma unroll
          for (int fi=0; fi<32; fi++){
            float a = af[fi];
            acc.x += a*w3r[fi].x; acc.y += a*w3r[fi].y;
            acc.z += a*w3r[fi].z; acc.w += a*w3r[fi].w;
          }
          uint2 pv;
          pv.x = pk2(fmaxf(acc.x,0.f), fmaxf(acc.y,0.f));
          pv.y = pk2(fmaxf(acc.z,0.f), fmaxf(acc.w,0.f));
          *(uint2*)((char*)h3buf + n*112 + tx*8) = pv;
        }
      }
    }
  }
  __syncthreads();

  {
    const char* h3buf = (const char*)regA;
    uint4* dst = (uint4*)(h3 + ((size_t)b*NN + base3*28)*F3);
    for (int t = tid; t < 1176; t += 256){
      int n = t/6, gq = t - n*6;
      dst[t] = *(const uint4*)(h3buf + n*112 + gq*16);
    }
  }
}

// Pipelined gumbel-softmax + einsum via MFMA. One block (4 waves) per sample.
// 13 chunks of 64 nodes; loads for chunk c+1 issued under MFMA(c).
// LDS 47,872 B -> 3 blocks/CU. Waves: ks=w>>1 (k-slice), mh=w&1 (mt half).
__global__ __launch_bounds__(256)
void einsum_mfma_kernel(const float* __restrict__ logits, const float* __restrict__ gumbel,
                        const bf16* __restrict__ h3, float* __restrict__ g){
  __shared__ __align__(16) char smem[47872];
  float* samp = (float*)smem;                    // [64][70] f32 linear
  short* stp  = (short*)(smem + 17920);          // [80][72] bf16 hi
  short* stlo = (short*)(smem + 29440);          // [80][72] bf16 lo
  short* htp  = (short*)(smem + 40960);          // [48][72] bf16
  float* cred = (float*)smem;                    // [80][49] aliases samp (dead by then)

  int b = blockIdx.x;
  int tid = threadIdx.x;
  int l = tid & 63, w = tid >> 6;
  int ks = w >> 1, mh = w & 1;
  int mtoff = mh ? 3 : 0, mtcnt = mh ? 2 : 3;
  int nl = tid >> 2, q = tid & 3;                // softmax: 4 lanes per node
  int st = (q < 2) ? q*18 : 36 + (q-2)*17;
  int cnt = (q < 2) ? 18 : 17;

  f32x4 acc[3][3];
  #pragma unroll
  for (int mt=0; mt<3; mt++)
    #pragma unroll
    for (int bt=0; bt<3; bt++) acc[mt][bt] = (f32x4){0.f,0.f,0.f,0.f};

  float4 xs[5];
  uint4 hv[2];

  auto do_loads = [&](int c){
    int c0 = c*64;
    int nv = (c == 12) ? 16 : 64;
    int lim4 = nv*70/4, limh = nv*6;
    const float4* l4 = (const float4*)(logits + ((size_t)b*NN + c0)*KK);
    const float4* g4 = (const float4*)(gumbel + ((size_t)b*NN + c0)*KK);
    #pragma unroll
    for (int s=0; s<5; s++){
      int t = tid + s*256;
      if (t < lim4){
        float4 lv = l4[t], gv = g4[t];
        xs[s] = (float4){2.f*(lv.x+gv.x), 2.f*(lv.y+gv.y), 2.f*(lv.z+gv.z), 2.f*(lv.w+gv.w)};
      } else xs[s] = (float4){0.f,0.f,0.f,0.f};
    }
    const uint4* h4 = (const uint4*)(h3 + ((size_t)b*NN + c0)*F3);
    #pragma unroll
    for (int s=0; s<2; s++){
      int t = tid + s*256;
      hv[s] = (t < limh) ? h4[t] : (uint4){0u,0u,0u,0u};
    }
  };

  auto write_samp = [&](){
    #pragma unroll
    for (int s=0; s<5; s++){
      int t = tid + s*256;
      if (t < 1120) ((float4*)samp)[t] = xs[s];
    }
  };

  auto softmax_writes = [&](int c){
    int nv = (c == 12) ? 16 : 64;
    float p[18];
    if (nl < nv){
      float x[18];
      float m = -1e30f;
      #pragma unroll
      for (int i=0; i<18; i++) if (i < cnt){ x[i] = samp[nl*70 + st + i]; m = fmaxf(m, x[i]); }
      m = fmaxf(m, __shfl_xor(m, 1));
      m = fmaxf(m, __shfl_xor(m, 2));
      float sum = 0.f;
      #pragma unroll
      for (int i=0; i<18; i++) if (i < cnt){ x[i] = __expf(x[i]-m); sum += x[i]; }
      sum += __shfl_xor(sum, 1);
      sum += __shfl_xor(sum, 2);
      float r = 1.0f/sum;
      #pragma unroll
      for (int i=0; i<18; i++) p[i] = x[i]*r;
    } else {
      #pragma unroll
      for (int i=0; i<18; i++) p[i] = 0.f;
    }
    #pragma unroll
    for (int i=0; i<18; i++) if (i < cnt){
      int k = st + i;
      short hi = bfbits(p[i]);
      union { short s; bf16 h; } uh; uh.s = hi;
      float lo = p[i] - __bfloat162float(uh.h);
      stp[k*72 + nl]  = hi;
      stlo[k*72 + nl] = bfbits(lo);
    }
    // ht transpose-write from staged regs
    #pragma unroll
    for (int s=0; s<2; s++){
      int t = tid + s*256;
      if (t < 384){
        int n = t/6, j = t - n*6, f0 = j*8;
        unsigned vv[4] = {hv[s].x, hv[s].y, hv[s].z, hv[s].w};
        #pragma unroll
        for (int i2=0; i2<4; i2++){
          htp[(f0+2*i2  )*72 + n] = (short)(vv[i2] & 0xFFFFu);
          htp[(f0+2*i2+1)*72 + n] = (short)(vv[i2] >> 16);
        }
      }
    }
  };

  auto do_mfma = [&](){
    int n0 = ks*32 + (l>>4)*8;
    #pragma unroll
    for (int bt=0; bt<3; bt++){
      s8v bfr = *(const s8v*)&htp[(bt*16 + (l&15))*72 + n0];
      #pragma unroll
      for (int mt=0; mt<3; mt++) if (mt < mtcnt){
        int row = (mtoff + mt)*16 + (l&15);
        s8v ah = *(const s8v*)&stp[row*72 + n0];
        s8v al = *(const s8v*)&stlo[row*72 + n0];
        acc[mt][bt] = __builtin_amdgcn_mfma_f32_16x16x32_bf16(ah, bfr, acc[mt][bt], 0, 0, 0);
        acc[mt][bt] = __builtin_amdgcn_mfma_f32_16x16x32_bf16(al, bfr, acc[mt][bt], 0, 0, 0);
      }
    }
  };

  // prologue: chunk 0
  do_loads(0);
  write_samp();
  __syncthreads();
  softmax_writes(0);
  __syncthreads();

  for (int c = 0; c < 13; c++){
    if (c < 12) do_loads(c+1);     // HBM latency hides under MFMA
    do_mfma();
    if (c < 12) write_samp();
    __syncthreads();
    if (c < 12){
      softmax_writes(c+1);
      __syncthreads();
    }
  }

  // cross-wave k-slice reduction into cred (aliases dead samp)
  if (ks == 0){
    #pragma unroll
    for (int mt=0; mt<3; mt++) if (mt < mtcnt)
      #pragma unroll
      for (int bt=0; bt<3; bt++)
        #pragma unroll
        for (int r=0; r<4; r++){
          int row = (mtoff+mt)*16 + (l>>4)*4 + r;
          int col = bt*16 + (l&15);
          cred[row*49 + col] = acc[mt][bt][r];
        }
  }
  __syncthreads();
  if (ks == 1){
    #pragma unroll
    for (int mt=0; mt<3; mt++) if (mt < mtcnt)
      #pragma unroll
      for (int bt=0; bt<3; bt++)
        #pragma unroll
        for (int r=0; r<4; r++){
          int row = (mtoff+mt)*16 + (l>>4)*4 + r;
          int col = bt*16 + (l&15);
          cred[row*49 + col] += acc[mt][bt][r];
        }
  }
  __syncthreads();
  for (int t = tid; t < KK*F3; t += 256){
    int r = t / F3, c2 = t - r*F3;
    g[(size_t)b*(KK*F3) + t] = cred[r*49 + c2];
  }
}

// Register-prefetch dense: out = act(A[f32, MxK] @ W[f32, KxN] + b).
template<int ACT>   // 0=relu, 1=sigmoid, 2=partial (no bias/act)
__global__ __launch_bounds__(256)
void dense_kernel(const float* __restrict__ A, const float* __restrict__ W,
                  const float* __restrict__ bias, float* __restrict__ out,
                  int M, int K, int Nn, int kChunk){
  __shared__ float As[16][65];
  __shared__ float Bs[16][64];
  int tx = threadIdx.x & 15, ty = threadIdx.x >> 4;
  int m0 = blockIdx.x*64, n0 = blockIdx.y*64;
  int ks = blockIdx.z * kChunk;
  int ke = min(K, ks + kChunk);
  int a_kk = threadIdx.x & 15, a_mm = threadIdx.x >> 4;
  int b_nn = threadIdx.x & 63, b_k0 = threadIdx.x >> 6;
  float ra[4], rb[4];
  float acc[4][4] = {};

  #pragma unroll
  for (int s=0; s<4; s++){
    int gk = ks + a_kk;
    ra[s] = (gk < ke) ? A[(size_t)(m0 + a_mm + s*16)*K + gk] : 0.f;
  }
  #pragma unroll
  for (int s=0; s<4; s++){
    int gk = ks + b_k0 + s*4, gn = n0 + b_nn;
    rb[s] = (gk < ke && gn < Nn) ? W[(size_t)gk*Nn + gn] : 0.f;
  }

  for (int k0 = ks; k0 < ke; k0 += 16){
    #pragma unroll
    for (int s=0; s<4; s++) As[a_kk][a_mm + s*16] = ra[s];
    #pragma unroll
    for (int s=0; s<4; s++) Bs[b_k0 + s*4][b_nn] = rb[s];
    __syncthreads();
    if (k0 + 16 < ke){
      #pragma unroll
      for (int s=0; s<4; s++){
        int gk = k0 + 16 + a_kk;
        ra[s] = (gk < ke) ? A[(size_t)(m0 + a_mm + s*16)*K + gk] : 0.f;
      }
      #pragma unroll
      for (int s=0; s<4; s++){
        int gk = k0 + 16 + b_k0 + s*4, gn = n0 + b_nn;
        rb[s] = (gk < ke && gn < Nn) ? W[(size_t)gk*Nn + gn] : 0.f;
      }
    }
    #pragma unroll
    for (int kk=0; kk<16; kk++){
      float a[4], bv[4];
      #pragma unroll
      for (int i2=0; i2<4; i2++) a[i2] = As[kk][ty*4+i2];
      #pragma unroll
      for (int j2=0; j2<4; j2++) bv[j2] = Bs[kk][tx*4+j2];
      #pragma unroll
      for (int i2=0; i2<4; i2++)
        #pragma unroll
        for (int j2=0; j2<4; j2++) acc[i2][j2] += a[i2]*bv[j2];
    }
    __syncthreads();
  }

  if (ACT == 2){
    float* po = out + (size_t)blockIdx.z*M*Nn;
    #pragma unroll
    for (int j2=0; j2<4; j2++){
      int gn = n0 + tx*4 + j2;
      if (gn < Nn){
        #pragma unroll
        for (int i2=0; i2<4; i2++)
          po[(size_t)(m0 + ty*4 + i2)*Nn + gn] = acc[i2][j2];
      }
    }
  } else {
    #pragma unroll
    for (int j2=0; j2<4; j2++){
      int gn = n0 + tx*4 + j2;
      if (gn < Nn){
        float bb = bias[gn];
        #pragma unroll
        for (int i2=0; i2<4; i2++){
          float v = acc[i2][j2] + bb;
          v = (ACT == 0) ? fmaxf(v, 0.f) : 1.0f/(1.0f + __expf(-v));
          out[(size_t)(m0 + ty*4 + i2)*Nn + gn] = v;
        }
      }
    }
  }
}

// split-K partial reduction + bias + relu
__global__ __launch_bounds__(256)
void reduce_bias_relu(const float* __restrict__ part, const float* __restrict__ bias,
                      float* __restrict__ out, int M, int Nn, int S){
  int idx = blockIdx.x*256 + threadIdx.x;
  if (idx >= M*Nn) return;
  int n = idx % Nn;
  float s = bias[n];
  for (int i=0; i<S; i++) s += part[(size_t)i*M*Nn + idx];
  out[idx] = fmaxf(s, 0.f);
}

// mu/var heads + reparameterize
__global__ __launch_bounds__(256)
void latent_kernel(const float* __restrict__ e2,
                   const float* __restrict__ Wmu, const float* __restrict__ bmu,
                   const float* __restrict__ Wvar, const float* __restrict__ bvar,
                   const float* __restrict__ eps, float* __restrict__ z){
  int idx = blockIdx.x*256 + threadIdx.x;
  int b = idx / ZD, zi = idx - b*ZD;
  const float* er = e2 + (size_t)b*HD;
  float amu = 0.f, avr = 0.f;
  for (int j=0; j<HD; j++){
    float e = er[j];
    amu += e*Wmu[j*ZD + zi];
    avr += e*Wvar[j*ZD + zi];
  }
  float mu = amu + bmu[zi];
  float va = avr + bvar[zi];
  float sp = fmaxf(va, 0.f) + log1pf(__expf(-fabsf(va)));
  z[idx] = mu + eps[idx]*sqrtf(sp + 1e-10f);
}

extern "C" void kernel_launch(void* const* d_in, const int* in_sizes, int n_in,
                              void* d_out, int out_size, void* d_ws, size_t ws_size,
                              hipStream_t stream){
  (void)in_sizes; (void)n_in; (void)out_size; (void)ws_size;
  const float* nodes  = (const float*)d_in[0];
  const float* logits = (const float*)d_in[1];
  const float* gumbel = (const float*)d_in[2];
  const float* eps    = (const float*)d_in[3];
  const float* W1 =(const float*)d_in[4],  *b1 =(const float*)d_in[5];
  const float* W2 =(const float*)d_in[6],  *b2 =(const float*)d_in[7];
  const float* W3 =(const float*)d_in[8],  *b3 =(const float*)d_in[9];
  const float* We1=(const float*)d_in[10], *be1=(const float*)d_in[11];
  const float* We2=(const float*)d_in[12], *be2=(const float*)d_in[13];
  const float* Wmu=(const float*)d_in[14], *bmu=(const float*)d_in[15];
  const float* Wvr=(const float*)d_in[16], *bvr=(const float*)d_in[17];
  const float* Wd1=(const float*)d_in[18], *bd1=(const float*)d_in[19];
  const float* Wd2=(const float*)d_in[20], *bd2=(const float*)d_in[21];
  // edge_src/edge_dst unused: grid graph handled analytically.

  char* ws = (char*)d_ws;
  bf16*  h3 = (bf16*)(ws);                 // B*N*48*2       = 77,070,336
  float* g  = (float*)(ws + 77070336);     // B*3360*4       = 13,762,560
  float* e1 = (float*)(ws + 90832896);
  float* e2 = (float*)(ws + 92471296);
  float* zb = (float*)(ws + 94109696);
  float* dd = (float*)(ws + 94396416);
  float* part = (float*)(ws);              // aliases h3 (dead by then)
  float* out = (float*)d_out;

  gcn_fused<<<4096, 256, 0, stream>>>(nodes, W1, b1, W2, b2, W3, b3, h3);
  einsum_mfma_kernel<<<1024, 256, 0, stream>>>(logits, gumbel, h3, g);
  dense_kernel<2><<<dim3(16, 7, 8), 256, 0, stream>>>(g, We1, nullptr, part, 1024, 3360, 400, 432);
  reduce_bias_relu<<<1600, 256, 0, stream>>>(part, be1, e1, 1024, 400, 8);
  dense_kernel<0><<<dim3(16, 7, 1), 256, 0, stream>>>(e1, We2, be2, e2, 1024, 400, 400, 400);
  latent_kernel<<<280, 256, 0, stream>>>(e2, Wmu, bmu, Wvr, bvr, eps, zb);
  dense_kernel<0><<<dim3(16, 7, 1), 256, 0, stream>>>(zb, Wd1, bd1, dd, 1024, 70, 400, 70);
  dense_kernel<1><<<dim3(16, 13, 1), 256, 0, stream>>>(dd, Wd2, bd2, out, 1024, 400, 784, 400);
}